// Round 12
// baseline (1010.569 us; speedup 1.0000x reference)
//
#include <hip/hip_runtime.h>

// ---------------------------------------------------------------------------
// MoChA monotonic chunkwise attention. B=16, K=2000(pad 2048), Q=256, D=1024,
// H=4, dk=256, W=8, SCALE=32.
// R6: mask bit-packed; LDS-transpose epilogue on all MFMA kernels.
// R10: BK=64, octet-distinct XOR staging swizzle (rule #21 both-sides).
// R13 k_scan: depth-8 chunk pipeline, ~107us (banked; a merged-barrier
// variant was REJECTED: vmcnt accounting with interleaved stores has a
// prologue-era race window - R11 failure class).
// R15 hybrid: k_proj/k_escore 2-buffer 64KB vmcnt(8) (2 blocks/CU);
// k_cv/k_out depth-2 96KB vmcnt(16) (grids <=256 blocks = 1/CU anyway).
// R16: single-stash epilogue - whole 128x128 f32 tile into 64KB LDS at once
// (same row-XOR swizzle; writes 2-way free, reads octet-spread), ONE barrier
// pair instead of 4 (saves 6 barriers + 3 phases/block; k_escore's epilogue
// was half its total barriers).
// Arena 285 MiB, ws_size-guarded.
// ---------------------------------------------------------------------------

typedef __bf16 bf16x8_t __attribute__((ext_vector_type(8)));
typedef float f32x4_t __attribute__((ext_vector_type(4)));
typedef unsigned short ushort8_t __attribute__((ext_vector_type(8)));
typedef unsigned short ushort4_t __attribute__((ext_vector_type(4)));
typedef unsigned int uint4_t __attribute__((ext_vector_type(4)));

__device__ __forceinline__ unsigned short f2bf(float x) {
  unsigned int u = __builtin_bit_cast(unsigned int, x);
  u += 0x7fffu + ((u >> 16) & 1u);  // RNE
  return (unsigned short)(u >> 16);
}
__device__ __forceinline__ float bf2f(unsigned short h) {
  unsigned int u = ((unsigned int)h) << 16;
  return __builtin_bit_cast(float, u);
}

// async 16B/lane global->LDS; lds dest must be wave-uniform base (+lane*16)
__device__ __forceinline__ void gld16(const unsigned short* g, unsigned short* l) {
  __builtin_amdgcn_global_load_lds(
      (const __attribute__((address_space(1))) void*)g,
      (__attribute__((address_space(3))) void*)l, 16, 0, 0);
}

// 64-lane inclusive prefix sum, 6 DPP steps (validated R3)
__device__ __forceinline__ float wave_incl_scan(float x) {
  float v = x;
  int mv;
#define DPP_ADD(ctrl, rmask, bctrl)                                           \
  mv = __builtin_amdgcn_update_dpp(0, __builtin_bit_cast(int, v), ctrl,       \
                                   rmask, 0xf, bctrl);                        \
  v += __builtin_bit_cast(float, mv);
  DPP_ADD(0x111, 0xf, true);   // row_shr:1
  DPP_ADD(0x112, 0xf, true);   // row_shr:2
  DPP_ADD(0x114, 0xf, true);   // row_shr:4
  DPP_ADD(0x118, 0xf, true);   // row_shr:8
  DPP_ADD(0x142, 0xa, false);  // bcast15 -> rows 1,3
  DPP_ADD(0x143, 0xc, false);  // bcast31 -> rows 2,3
#undef DPP_ADD
  return v;
}

// wave max, broadcast to all lanes
__device__ __forceinline__ float wave_max_bcast(float x) {
  const float NI = -__builtin_inff();
  float v = x;
  int mv;
#define DPP_MAX(ctrl, rmask)                                                  \
  mv = __builtin_amdgcn_update_dpp(__builtin_bit_cast(int, NI),               \
                                   __builtin_bit_cast(int, v), ctrl, rmask,   \
                                   0xf, false);                               \
  v = fmaxf(v, __builtin_bit_cast(float, mv));
  DPP_MAX(0x111, 0xf) DPP_MAX(0x112, 0xf) DPP_MAX(0x114, 0xf)
  DPP_MAX(0x118, 0xf) DPP_MAX(0x142, 0xa) DPP_MAX(0x143, 0xc)
#undef DPP_MAX
  int r = __builtin_amdgcn_readlane(__builtin_bit_cast(int, v), 63);
  return __builtin_bit_cast(float, r);
}

#define WSHR1(dst, src)                                                       \
  {                                                                           \
    int _t = __builtin_amdgcn_update_dpp(0, __builtin_bit_cast(int, src),     \
                                         0x138, 0xf, 0xf, true);              \
    dst = __builtin_bit_cast(float, _t);                                      \
  }
#define WSHL1(dst, src)                                                       \
  {                                                                           \
    int _t = __builtin_amdgcn_update_dpp(0, __builtin_bit_cast(int, src),     \
                                         0x130, 0xf, 0xf, true);              \
    dst = __builtin_bit_cast(float, _t);                                      \
  }

// ---- staging helper: one 128x64 half-tile pair, 8 gld16 per wave ----------
__device__ __forceinline__ void gemm_stage(const unsigned short* Ag, long lda,
                                           const unsigned short* Bg, long ldb,
                                           int wid, unsigned short* lA,
                                           unsigned short* lB) {
#pragma unroll
  for (int r = 0; r < 4; ++r) {
    gld16(Ag + (long)(r * 8) * lda, lA + (wid * 32 + r * 8) * 64);
    gld16(Bg + (long)(r * 8) * ldb, lB + (wid * 32 + r * 8) * 64);
  }
}

// ---- shared fragment-read + MFMA for one BK=64 tile -----------------------
__device__ __forceinline__ void gemm_compute(const unsigned short* cA,
                                             const unsigned short* cB,
                                             int wm, int wn, int lr, int quad,
                                             int rs, f32x4_t acc[4][4]) {
#pragma unroll
  for (int kk = 0; kk < 2; ++kk) {
    bf16x8_t afr[4], bfr[4];
#pragma unroll
    for (int i = 0; i < 4; ++i)
      afr[i] = *(const bf16x8_t*)(cA + (wm * 64 + i * 16 + lr) * 64 +
                                  (((kk * 4 + quad) ^ rs) << 3));
#pragma unroll
    for (int j = 0; j < 4; ++j)
      bfr[j] = *(const bf16x8_t*)(cB + (wn * 64 + j * 16 + lr) * 64 +
                                  (((kk * 4 + quad) ^ rs) << 3));
#pragma unroll
    for (int i = 0; i < 4; ++i)
#pragma unroll
      for (int j = 0; j < 4; ++j)
        acc[i][j] = __builtin_amdgcn_mfma_f32_16x16x32_bf16(afr[i], bfr[j], acc[i][j], 0, 0, 0);
  }
}

// ---- R12 tile: BK=64, 1-ahead counted-vmcnt, 2 buffers (64KB) -------------
// For high-block-count kernels (k_proj/k_escore): keeps 2 blocks/CU.
__device__ __forceinline__ void gemm_bt_tile(
    const unsigned short* __restrict__ A, long lda,
    const unsigned short* __restrict__ B, long ldb, int Kd,
    char* smem, f32x4_t acc[4][4]) {
  const int tid = threadIdx.x;
  const int lane = tid & 63;
  const int wid = tid >> 6;
  const int wm = wid >> 1, wn = wid & 1;
  const int lr = lane & 15, quad = lane >> 4;
  const int srow = wid * 32 + (lane >> 3);          // base staging row
  const int scol = ((lane & 7) ^ (lane >> 3)) * 8;  // pre-swizzled src granule
  const int rs = lr & 7;                            // read-side XOR key
  const unsigned short* Ag = A + (long)srow * lda + scol;
  const unsigned short* Bg = B + (long)srow * ldb + scol;
  const int nt = Kd >> 6;
  gemm_stage(Ag, lda, Bg, ldb, wid,
             (unsigned short*)smem, (unsigned short*)(smem + 16384));
  for (int t = 0; t < nt; ++t) {
    const unsigned short* cA = (const unsigned short*)(smem + (t & 1) * 32768);
    const unsigned short* cB = (const unsigned short*)(smem + (t & 1) * 32768 + 16384);
    if (t + 1 < nt) {
      unsigned short* nA = (unsigned short*)(smem + ((t + 1) & 1) * 32768);
      unsigned short* nB = (unsigned short*)(smem + ((t + 1) & 1) * 32768 + 16384);
      gemm_stage(Ag + (t + 1) * 64, lda, Bg + (t + 1) * 64, ldb, wid, nA, nB);
      asm volatile("s_waitcnt vmcnt(8)" ::: "memory");
    } else {
      asm volatile("s_waitcnt vmcnt(0)" ::: "memory");
    }
    __builtin_amdgcn_s_barrier();
    asm volatile("" ::: "memory");
    gemm_compute(cA, cB, wm, wn, lr, quad, rs, acc);
    asm volatile("" ::: "memory");
    __builtin_amdgcn_s_barrier();
  }
}

// ---- depth-2 tile: BK=64, 2-ahead counted-vmcnt, 3 buffers (96KB) ---------
// ONLY for grids <= 256 blocks (1 block/CU regardless of LDS): k_cv, k_out.
__device__ __forceinline__ void gemm_bt_tile_d2(
    const unsigned short* __restrict__ A, long lda,
    const unsigned short* __restrict__ B, long ldb, int Kd,
    char* smem, f32x4_t acc[4][4]) {
  const int tid = threadIdx.x;
  const int lane = tid & 63;
  const int wid = tid >> 6;
  const int wm = wid >> 1, wn = wid & 1;
  const int lr = lane & 15, quad = lane >> 4;
  const int srow = wid * 32 + (lane >> 3);
  const int scol = ((lane & 7) ^ (lane >> 3)) * 8;
  const int rs = lr & 7;
  const unsigned short* Ag = A + (long)srow * lda + scol;
  const unsigned short* Bg = B + (long)srow * ldb + scol;
  const int nt = Kd >> 6;
  gemm_stage(Ag, lda, Bg, ldb, wid,
             (unsigned short*)smem, (unsigned short*)(smem + 16384));
  gemm_stage(Ag + 64, lda, Bg + 64, ldb, wid,
             (unsigned short*)(smem + 32768), (unsigned short*)(smem + 49152));
  for (int t = 0; t < nt; ++t) {
    int bc = t % 3;
    const unsigned short* cA = (const unsigned short*)(smem + bc * 32768);
    const unsigned short* cB = (const unsigned short*)(smem + bc * 32768 + 16384);
    if (t + 2 < nt) {
      int bn = (t + 2) % 3;
      unsigned short* nA = (unsigned short*)(smem + bn * 32768);
      unsigned short* nB = (unsigned short*)(smem + bn * 32768 + 16384);
      gemm_stage(Ag + (t + 2) * 64, lda, Bg + (t + 2) * 64, ldb, wid, nA, nB);
      asm volatile("s_waitcnt vmcnt(16)" ::: "memory");
    } else if (t + 1 < nt) {
      asm volatile("s_waitcnt vmcnt(8)" ::: "memory");
    } else {
      asm volatile("s_waitcnt vmcnt(0)" ::: "memory");
    }
    __builtin_amdgcn_s_barrier();
    asm volatile("" ::: "memory");
    gemm_compute(cA, cB, wm, wn, lr, quad, rs, acc);
    asm volatile("" ::: "memory");
    __builtin_amdgcn_s_barrier();
  }
}

#define EPILOGUE_IDX()                                          \
  const int tid = threadIdx.x, lane = tid & 63, wid = tid >> 6; \
  const int wm = wid >> 1, wn = wid & 1, lr = lane & 15, quad = lane >> 4;

#define ACC_INIT()                              \
  f32x4_t acc[4][4];                            \
  _Pragma("unroll") for (int i = 0; i < 4; ++i) \
  _Pragma("unroll") for (int j = 0; j < 4; ++j) \
  _Pragma("unroll") for (int r = 0; r < 4; ++r) acc[i][j][r] = 0.f;

#define GEMM_SMEM2()                                        \
  __shared__ __attribute__((aligned(16))) char smem[65536]; \
  float* lT = (float*)smem;

#define GEMM_SMEM3()                                        \
  __shared__ __attribute__((aligned(16))) char smem[98304]; \
  float* lT = (float*)smem;

// ---- single-stash transpose epilogue (R16) --------------------------------
// Whole 128x128 f32 tile to LDS (64KB) in one phase. Swizzle: granule index
// ^= (row&7) -> writes 2-way per bank (free), f32x4 reads octet-distinct.
// The tile loop ends with an s_barrier, so stash needs no leading barrier.
__device__ __forceinline__ void epi_stash_all(float* lT, f32x4_t (&acc)[4][4],
                                              int wm, int wn, int lr, int quad) {
#pragma unroll
  for (int i = 0; i < 4; ++i)
#pragma unroll
    for (int j = 0; j < 4; ++j) {
      int lcol = wn * 64 + j * 16 + lr;
#pragma unroll
      for (int r = 0; r < 4; ++r) {
        int lrow = wm * 64 + i * 16 + quad * 4 + r;
        lT[lrow * 128 + (((lcol >> 2) ^ (lrow & 7)) << 2) + (lcol & 3)] = acc[i][j][r];
      }
    }
}
__device__ __forceinline__ f32x4_t epi_read(const float* lT, int tr, int col4) {
  return *(const f32x4_t*)&lT[tr * 128 + ((col4 ^ (tr & 7)) << 2)];
}

// ---- projection: C_bf16 = bf16(A_bf @ Wt^T + bias), N=1024, 1D swizzled ---
__global__ __launch_bounds__(256) void k_proj(const unsigned short* __restrict__ A,
                                              const unsigned short* __restrict__ Wt,
                                              const float* __restrict__ bias,
                                              unsigned short* __restrict__ C) {
  GEMM_SMEM2();
  ACC_INIT();
  int flat = blockIdx.x;
  int mb = (flat >> 6) * 8 + (flat & 7);
  int nb = (flat >> 3) & 7;
  const unsigned short* Ab = A + (long)mb * 128 * 1024;
  const unsigned short* Bb = Wt + (long)nb * 128 * 1024;
  gemm_bt_tile(Ab, 1024, Bb, 1024, 1024, smem, acc);
  EPILOGUE_IDX();
  (void)lane;
  long mbase = (long)mb * 128;
  int nbase = nb * 128;
  const int rloc = tid >> 3, c7 = tid & 7;
  epi_stash_all(lT, acc, wm, wn, lr, quad);
  __syncthreads();
#pragma unroll
  for (int i = 0; i < 4; ++i) {
    int tr = (rloc >> 4) * 64 + i * 16 + (rloc & 15);
    long mg = mbase + tr;
    unsigned short* crow = C + mg * 1024 + nbase;
    const float* brow = bias + nbase;
#pragma unroll
    for (int m = 0; m < 4; ++m) {
      int col4 = c7 + 8 * m;
      f32x4_t v = epi_read(lT, tr, col4);
      f32x4_t bv = *(const f32x4_t*)&brow[col4 * 4];
      ushort4_t o;
#pragma unroll
      for (int z = 0; z < 4; ++z) o[z] = f2bf(v[z] + bv[z]);
      *(ushort4_t*)(crow + col4 * 4) = o;
    }
  }
}

// ---- mask int32 [16][256][2000] -> packed bits [16*256][64 words] ---------
__global__ __launch_bounds__(256) void k_maskpack(const int* __restrict__ mask,
                                                  unsigned int* __restrict__ mw) {
  int lane = threadIdx.x & 63, wid = threadIdx.x >> 6;
  int row = blockIdx.x * 4 + wid;  // 0..4095 = b*256+q
  const int* mp = mask + (long)row * 2000;
  unsigned int* op = mw + (long)row * 64;
  for (int c = 0; c < 32; ++c) {
    int k = c * 64 + lane;
    int v = (k < 2000) ? mp[k] : 0;
    unsigned long long b = __ballot(v != 0);
    if (lane == 0) {
      op[c * 2] = (unsigned int)b;
      op[c * 2 + 1] = (unsigned int)(b >> 32);
    }
  }
}

// ---- attention scores -> bf16. kproj padded to 2048 rows/batch ------------
__global__ __launch_bounds__(256) void k_escore(const unsigned short* __restrict__ qproj,
                                                const unsigned short* __restrict__ kproj,
                                                const unsigned int* __restrict__ maskw,
                                                const float* __restrict__ rptr,
                                                unsigned short* __restrict__ outp, int is_ma) {
  GEMM_SMEM2();
  ACC_INIT();
  int bz = blockIdx.z, b = bz >> 2, h = bz & 3;
  int nrow0 = blockIdx.x * 128;
  const unsigned short* Ab = qproj + ((long)b * 256 + blockIdx.y * 128) * 1024 + h * 256;
  const unsigned short* Bb = kproj + ((long)b * 2048 + nrow0) * 1024 + h * 256;
  gemm_bt_tile(Ab, 1024, Bb, 1024, 256, smem, acc);
  float rv = is_ma ? rptr[0] : 0.f;
  EPILOGUE_IDX();
  (void)lane;
  const int rloc = tid >> 3, c7 = tid & 7;
  epi_stash_all(lT, acc, wm, wn, lr, quad);
  __syncthreads();
#pragma unroll
  for (int i = 0; i < 4; ++i) {
    int tr = (rloc >> 4) * 64 + i * 16 + (rloc & 15);
    int qg = blockIdx.y * 128 + tr;
    uint4_t mw4 = *(const uint4_t*)(maskw + (((long)b * 256 + qg) << 6) + (nrow0 >> 5));
    unsigned short* orow = outp + ((long)bz * 256 + qg) * 2048 + nrow0;
#pragma unroll
    for (int m = 0; m < 4; ++m) {
      int col4 = c7 + 8 * m;
      f32x4_t v = epi_read(lT, tr, col4);
      unsigned int bits = (mw4[m] >> (4 * c7)) & 0xFu;
      ushort4_t o;
#pragma unroll
      for (int z = 0; z < 4; ++z) {
        float e = v[z] * 0.03125f;
        bool valid = (bits >> z) & 1u;
        float ov;
        if (is_ma)
          ov = valid ? (1.f / (1.f + __expf(-(e + rv)))) : 0.f;
        else
          ov = valid ? e : -1e9f;
        o[z] = f2bf(ov);
      }
      *(ushort4_t*)(orow + col4 * 4) = o;
    }
  }
}

// ---- cp = exp(exclusive_cumsum_k(log(clip(1-p)))), bf16, parallel ---------
__global__ __launch_bounds__(256) void k_cp(const unsigned short* __restrict__ p,
                                            unsigned short* __restrict__ cp) {
  __shared__ float wsum[4];
  long base = (long)blockIdx.x * 2048;
  int tid = threadIdx.x, lane = tid & 63, wid = tid >> 6;
  ushort8_t p8 = *(const ushort8_t*)(p + base + tid * 8);
  float lex[8], s1 = 0.f;
#pragma unroll
  for (int i = 0; i < 8; ++i) {
    float om = fminf(fmaxf(1.f - bf2f((unsigned short)p8[i]), 1e-6f), 1.f);
    lex[i] = s1;
    s1 += __logf(om);
  }
  float incl = wave_incl_scan(s1);
  if (lane == 63) wsum[wid] = incl;
  __syncthreads();
  float off = incl - s1;
  if (wid > 0) off += wsum[0];
  if (wid > 1) off += wsum[1];
  if (wid > 2) off += wsum[2];
  ushort8_t o;
#pragma unroll
  for (int i = 0; i < 8; ++i) o[i] = f2bf(__expf(off + lex[i]));
  *(ushort8_t*)(cp + base + tid * 8) = o;
}

// ---- sequential scan over q; cp MAY ALIAS alpha (row read before write) ---
// R13: depth-8 chunk pipeline, uniform schedule (banked at ~107us).
__global__ __launch_bounds__(256) void k_scan(const unsigned short* __restrict__ p,
                                              const unsigned short* cp,
                                              const float* __restrict__ awp,
                                              unsigned short* alpha) {
  __shared__ unsigned short lsp[8][2][2048];
  __shared__ unsigned short lsc[8][2][2048];
  __shared__ float wsum[2][4];
  int bh = blockIdx.x;
  int tid = threadIdx.x, lane = tid & 63, w = tid >> 6;
  long base = (long)bh * 256 * 2048;
  float aw[8];
  const float* ap = awp + (long)bh * 2000;
#pragma unroll
  for (int i = 0; i < 8; ++i) {
    int k = tid * 8 + i;
    aw[i] = (k < 2000) ? ap[k] : 0.f;
  }
  const unsigned short* pg = p + base;
  const unsigned short* cg = cp + base;
  unsigned short* ag = alpha + base;
  const int sa = w >> 1;  // 0 -> stage p, 1 -> stage cp
  const int sr = w & 1;   // chunk-local row this wave stages
  const unsigned short* sbase = (sa ? cg : pg) + (long)sr * 2048 + lane * 8;
#define STAGE(c, b)                                                           \
  {                                                                           \
    const unsigned short* _src = sbase + (long)(c) * 2 * 2048;                \
    unsigned short* _dst = sa ? &lsc[b][sr][0] : &lsp[b][sr][0];              \
    _Pragma("unroll") for (int _q = 0; _q < 4; ++_q)                          \
        gld16(_src + _q * 512, _dst + _q * 512);                              \
  }
#pragma unroll
  for (int c0 = 0; c0 < 7; ++c0) STAGE(c0, c0);
  for (int c = 0; c < 128; ++c) {
    const int b = c & 7;
    {
      int cc = c + 7;
      int bb = cc & 7;
      if (cc > 127) cc = 127;  // tail: re-stage last chunk into dead buffer
      STAGE(cc, bb);
    }
    asm volatile("s_waitcnt vmcnt(28)" ::: "memory");
    __builtin_amdgcn_s_barrier();
    asm volatile("" ::: "memory");
#pragma unroll
    for (int cr = 0; cr < 2; ++cr) {
      const int q = c * 2 + cr;
      ushort8_t p8 = *(const ushort8_t*)&lsp[b][cr][tid * 8];
      ushort8_t c8 = *(const ushort8_t*)&lsc[b][cr][tid * 8];
      float pc[8], rd[8];
#pragma unroll
      for (int i = 0; i < 8; ++i) {
        float pv = bf2f((unsigned short)p8[i]);
        float cv = bf2f((unsigned short)c8[i]);
        pc[i] = pv * cv;
        rd[i] = __builtin_amdgcn_rcpf(fminf(fmaxf(cv, 1e-6f), 1.f));
      }
      float t[8], s1 = 0.f;
#pragma unroll
      for (int i = 0; i < 8; ++i) {
        s1 = fmaf(aw[i], rd[i], s1);
        t[i] = s1;
      }
      float incl = wave_incl_scan(s1);
      if (lane == 63) wsum[q & 1][w] = incl;
      asm volatile("s_waitcnt lgkmcnt(0)" ::: "memory");
      __builtin_amdgcn_s_barrier();
      asm volatile("" ::: "memory");
      float off = incl - s1;
      if (w > 0) off += wsum[q & 1][0];
      if (w > 1) off += wsum[q & 1][1];
      if (w > 2) off += wsum[q & 1][2];
      ushort8_t o;
#pragma unroll
      for (int i = 0; i < 8; ++i) {
        aw[i] = pc[i] * (t[i] + off);
        o[i] = f2bf(aw[i]);
      }
      *(ushort8_t*)(ag + (long)q * 2048 + tid * 8) = o;
    }
  }
#undef STAGE
}

// ---- beta = se * movsum_fwd7(alpha / movsum_back7(se)); register/DPP ------
__global__ __launch_bounds__(256) void k_beta(unsigned short* eca,
                                              const unsigned short* __restrict__ alpha) {
  __shared__ float red[4];
  __shared__ float edgeB[4][8];
  __shared__ float edgeF[4][8];
  long base = (long)blockIdx.x * 2048 + threadIdx.x * 8;
  int tid = threadIdx.x, lane = tid & 63, wid = tid >> 6;
  (void)tid;
  ushort8_t u8 = *(const ushort8_t*)(eca + base);
  ushort8_t a8 = *(const ushort8_t*)(alpha + base);
  float u[8], a[8];
#pragma unroll
  for (int i = 0; i < 8; ++i) {
    u[i] = bf2f((unsigned short)u8[i]);
    a[i] = bf2f((unsigned short)a8[i]);
  }
  // block max
  float m = u[0];
#pragma unroll
  for (int i = 1; i < 8; ++i) m = fmaxf(m, u[i]);
  m = wave_max_bcast(m);
  if (lane == 0) red[wid] = m;
  __syncthreads();
  m = fmaxf(fmaxf(red[0], red[1]), fmaxf(red[2], red[3]));
  // se + local prefix lp
  float se[8], lp[8];
  float s = 0.f;
#pragma unroll
  for (int i = 0; i < 8; ++i) {
    se[i] = fmaxf(__expf(u[i] - m), 1e-5f);
    s += se[i];
    lp[i] = s;
  }
  // prev-lane lp (wave_shr:1), cross-wave patch via LDS
  float plp[8];
#pragma unroll
  for (int i = 0; i < 8; ++i) WSHR1(plp[i], lp[i]);
  if (lane == 63) {
#pragma unroll
    for (int i = 0; i < 8; ++i) edgeB[wid][i] = lp[i];
  }
  __syncthreads();
  if (lane == 0 && wid > 0) {
#pragma unroll
    for (int i = 0; i < 8; ++i) plp[i] = edgeB[wid - 1][i];
  }
  // msb = lp[i] + prevTotal - prevlp[i]; sra = a/msb; local prefix lf
  float sra[8], lf[8];
  s = 0.f;
#pragma unroll
  for (int i = 0; i < 8; ++i) {
    float msb = lp[i] + plp[7] - plp[i];
    sra[i] = a[i] * __builtin_amdgcn_rcpf(msb);
    s += sra[i];
    lf[i] = s;
  }
  // next-lane lf (wave_shl:1), cross-wave patch
  float nlf[8];
#pragma unroll
  for (int i = 0; i < 8; ++i) WSHL1(nlf[i], lf[i]);
  if (lane == 0) {
#pragma unroll
    for (int i = 0; i < 8; ++i) edgeF[wid][i] = lf[i];
  }
  __syncthreads();
  if (lane == 63 && wid < 3) {
#pragma unroll
    for (int i = 0; i < 8; ++i) nlf[i] = edgeF[wid + 1][i];
  }
  ushort8_t o;
#pragma unroll
  for (int i = 0; i < 8; ++i) {
    float own = lf[7] - (i ? lf[i - 1] : 0.f);
    float nxt = i ? nlf[i - 1] : 0.f;
    o[i] = f2bf(se[i] * (own + nxt));
  }
  *(ushort8_t*)(eca + base) = o;
}

// ---- vT[bz][d][k] = vproj[(b*2048+k)*1024 + h*256+d] ----------------------
__global__ __launch_bounds__(256) void k_build_vT(const unsigned short* __restrict__ v,
                                                  unsigned short* __restrict__ vT) {
  __shared__ unsigned short t[64][68];
  int bz = blockIdx.z, b = bz >> 2, h = bz & 3;
  int k0 = blockIdx.x * 64, d0 = blockIdx.y * 64;
  int tx = threadIdx.x & 63, tg = threadIdx.x >> 6;
#pragma unroll
  for (int i = 0; i < 16; ++i) {
    int kk = tg * 16 + i;
    t[kk][tx] = v[((long)(b * 2048 + k0 + kk)) * 1024 + h * 256 + d0 + tx];
  }
  __syncthreads();
#pragma unroll
  for (int i = 0; i < 16; ++i) {
    int dd = tg * 16 + i;
    vT[((long)bz * 256 + d0 + dd) * 2048 + k0 + tx] = t[tx][dd];
  }
}

// ---- cv = beta @ v (per bz: 256x2048 @ 2048x256), bf16 out ----------------
__global__ __launch_bounds__(256) void k_cv(const unsigned short* __restrict__ beta,
                                            const unsigned short* __restrict__ vT,
                                            unsigned short* __restrict__ cv) {
  GEMM_SMEM3();
  ACC_INIT();
  int bz = blockIdx.z, b = bz >> 2, h = bz & 3;
  const unsigned short* Ab = beta + (long)bz * 256 * 2048 + (long)blockIdx.y * 128 * 2048;
  const unsigned short* Bb = vT + (long)bz * 256 * 2048 + (long)blockIdx.x * 128 * 2048;
  gemm_bt_tile_d2(Ab, 2048, Bb, 2048, 2048, smem, acc);
  EPILOGUE_IDX();
  (void)lane;
  const int rloc = tid >> 3, c7 = tid & 7;
  epi_stash_all(lT, acc, wm, wn, lr, quad);
  __syncthreads();
#pragma unroll
  for (int i = 0; i < 4; ++i) {
    int tr = (rloc >> 4) * 64 + i * 16 + (rloc & 15);
    long mg = (long)b * 256 + blockIdx.y * 128 + tr;
    unsigned short* crow = cv + mg * 1024 + h * 256 + blockIdx.x * 128;
#pragma unroll
    for (int m = 0; m < 4; ++m) {
      int col4 = c7 + 8 * m;
      f32x4_t v = epi_read(lT, tr, col4);
      ushort4_t o;
#pragma unroll
      for (int z = 0; z < 4; ++z) o[z] = f2bf(v[z]);
      *(ushort4_t*)(crow + col4 * 4) = o;
    }
  }
}

// ---- out = cv @ WoT^T + bo, fp32, M=4096 N=1024 ---------------------------
__global__ __launch_bounds__(256) void k_out(const unsigned short* __restrict__ cv,
                                             const unsigned short* __restrict__ WoT,
                                             const float* __restrict__ bo,
                                             float* __restrict__ outp) {
  GEMM_SMEM3();
  ACC_INIT();
  const unsigned short* Ab = cv + (long)blockIdx.y * 128 * 1024;
  const unsigned short* Bb = WoT + (long)blockIdx.x * 128 * 1024;
  gemm_bt_tile_d2(Ab, 1024, Bb, 1024, 1024, smem, acc);
  EPILOGUE_IDX();
  (void)lane;
  const int rloc = tid >> 3, c7 = tid & 7;
  epi_stash_all(lT, acc, wm, wn, lr, quad);
  __syncthreads();
#pragma unroll
  for (int i = 0; i < 4; ++i) {
    int tr = (rloc >> 4) * 64 + i * 16 + (rloc & 15);
    long mg = (long)blockIdx.y * 128 + tr;
    float* orow = outp + mg * 1024 + blockIdx.x * 128;
    const float* brow = bo + blockIdx.x * 128;
#pragma unroll
    for (int m = 0; m < 4; ++m) {
      int col4 = c7 + 8 * m;
      f32x4_t v = epi_read(lT, tr, col4);
      f32x4_t bv = *(const f32x4_t*)&brow[col4 * 4];
      *(f32x4_t*)&orow[col4 * 4] = v + bv;
    }
  }
}

// ---- W(1024x1024 f32) -> Wt bf16, Wt[n][d] = W[d][n] ----------------------
__global__ __launch_bounds__(256) void k_twT(const float* __restrict__ W,
                                             unsigned short* __restrict__ Wt) {
  __shared__ float t[32][33];
  int bx = blockIdx.x, by = blockIdx.y;
  int lx = threadIdx.x & 31, ly = threadIdx.x >> 5;
#pragma unroll
  for (int r = 0; r < 4; ++r)
    t[ly + 8 * r][lx] = W[((long)(by * 32 + ly + 8 * r)) * 1024 + bx * 32 + lx];
  __syncthreads();
#pragma unroll
  for (int r = 0; r < 4; ++r)
    Wt[((long)(bx * 32 + ly + 8 * r)) * 1024 + by * 32 + lx] = f2bf(t[lx][ly + 8 * r]);
}

// ---- fp32 [16][2000][1024] -> bf16 [16][2048][1024], pads zero ------------
__global__ __launch_bounds__(256) void k_cvt_pad(const float* __restrict__ src,
                                                 unsigned short* __restrict__ dst) {
  long idx = (long)blockIdx.x * 256 + threadIdx.x;  // 8-elem chunks
  int b = (int)(idx >> 18);                         // 262144 chunks / batch
  int rem = (int)(idx & 262143);
  int row = rem >> 7;
  int c8 = rem & 127;
  ushort8_t o;
  if (row < 2000) {
    const float* sp = src + ((long)(b * 2000 + row)) * 1024 + c8 * 8;
    float4 f0 = *(const float4*)sp;
    float4 f1 = *(const float4*)(sp + 4);
    o[0] = f2bf(f0.x); o[1] = f2bf(f0.y); o[2] = f2bf(f0.z); o[3] = f2bf(f0.w);
    o[4] = f2bf(f1.x); o[5] = f2bf(f1.y); o[6] = f2bf(f1.z); o[7] = f2bf(f1.w);
  } else {
#pragma unroll
    for (int z = 0; z < 8; ++z) o[z] = 0;
  }
  *(ushort8_t*)(dst + idx * 8) = o;
}

// ---- fp32 -> bf16 plain (query) -------------------------------------------
__global__ __launch_bounds__(256) void k_cvt(const float* __restrict__ src,
                                             unsigned short* __restrict__ dst) {
  long idx = (long)blockIdx.x * 256 + threadIdx.x;
  const float* sp = src + idx * 8;
  float4 f0 = *(const float4*)sp;
  float4 f1 = *(const float4*)(sp + 4);
  ushort8_t o;
  o[0] = f2bf(f0.x); o[1] = f2bf(f0.y); o[2] = f2bf(f0.z); o[3] = f2bf(f0.w);
  o[4] = f2bf(f1.x); o[5] = f2bf(f1.y); o[6] = f2bf(f1.z); o[7] = f2bf(f1.w);
  *(ushort8_t*)(dst + idx * 8) = o;
}

// ---------------------------------------------------------------------------
extern "C" void kernel_launch(void* const* d_in, const int* in_sizes, int n_in,
                              void* d_out, int out_size, void* d_ws, size_t ws_size,
                              hipStream_t stream) {
  const float* key = (const float*)d_in[0];
  const float* value = (const float*)d_in[1];
  const float* query = (const float*)d_in[2];
  const int* mask = (const int*)d_in[3];
  const float* awp = (const float*)d_in[4];
  const float* Wk_ma = (const float*)d_in[5];
  const float* bk_ma = (const float*)d_in[6];
  const float* Wq_ma = (const float*)d_in[7];
  const float* bq_ma = (const float*)d_in[8];
  const float* rvec = (const float*)d_in[9];
  const float* Wk_ca = (const float*)d_in[10];
  const float* bk_ca = (const float*)d_in[11];
  const float* Wq_ca = (const float*)d_in[12];
  const float* bq_ca = (const float*)d_in[13];
  const float* Wv = (const float*)d_in[14];
  const float* bv = (const float*)d_in[15];
  const float* Wo = (const float*)d_in[16];
  const float* bo = (const float*)d_in[17];
  float* outp = (float*)d_out;
  (void)in_sizes; (void)n_in; (void)out_size;

  // arena, 285 MiB
  char* ws = (char*)d_ws;
  size_t off = 0;
  auto alloc = [&](size_t bytes) {
    void* pp = ws + off;
    off += (bytes + 255) & ~(size_t)255;
    return pp;
  };
  unsigned short* wt[6];
  for (int i = 0; i < 6; ++i) wt[i] = (unsigned short*)alloc(1024L * 1024 * 2);
  unsigned short* xbf = (unsigned short*)alloc(16L * 2048 * 1024 * 2);   // key_bf -> value_bf
  unsigned short* qbf = (unsigned short*)alloc(4096L * 1024 * 2);        // query_bf -> cv
  unsigned short* kproj = (unsigned short*)alloc(16L * 2048 * 1024 * 2); // k_ma -> k_ca -> v
  unsigned short* qproj = (unsigned short*)alloc(4096L * 1024 * 2);      // q_ma -> q_ca
  unsigned short* bufP = (unsigned short*)alloc(64L * 256 * 2048 * 2);   // p -> eca -> beta
  unsigned short* bufA = (unsigned short*)alloc(64L * 256 * 2048 * 2);   // cp -> alpha -> vT
  unsigned int* maskw = (unsigned int*)alloc(4096L * 64 * 4);            // packed mask bits
  if (ws_size < off) return;  // fail via absmax, not a fault
  unsigned short* cv_bf = qbf;

  dim3 blk(256);
  // weights + input conversion
  k_twT<<<dim3(32, 32), blk, 0, stream>>>(Wk_ma, wt[0]);
  k_twT<<<dim3(32, 32), blk, 0, stream>>>(Wq_ma, wt[1]);
  k_twT<<<dim3(32, 32), blk, 0, stream>>>(Wk_ca, wt[2]);
  k_twT<<<dim3(32, 32), blk, 0, stream>>>(Wq_ca, wt[3]);
  k_twT<<<dim3(32, 32), blk, 0, stream>>>(Wv, wt[4]);
  k_twT<<<dim3(32, 32), blk, 0, stream>>>(Wo, wt[5]);
  k_maskpack<<<dim3(1024), blk, 0, stream>>>(mask, maskw);
  k_cvt_pad<<<dim3(16384), blk, 0, stream>>>(key, xbf);
  k_cvt<<<dim3(2048), blk, 0, stream>>>(query, qbf);
  // MA path
  k_proj<<<dim3(2048), blk, 0, stream>>>(xbf, wt[0], bk_ma, kproj);
  k_proj<<<dim3(256), blk, 0, stream>>>(qbf, wt[1], bq_ma, qproj);
  k_escore<<<dim3(16, 2, 64), blk, 0, stream>>>(qproj, kproj, maskw, rvec, bufP, 1);
  k_cp<<<dim3(16384), blk, 0, stream>>>(bufP, bufA);
  // CA projections (k_ma/q_ma dead; cp lives in bufA)
  k_proj<<<dim3(2048), blk, 0, stream>>>(xbf, wt[2], bk_ca, kproj);
  k_proj<<<dim3(256), blk, 0, stream>>>(qbf, wt[3], bq_ca, qproj);
  // scan: alpha overwrites cp row-by-row (read-before-write)
  k_scan<<<dim3(64), blk, 0, stream>>>(bufP, bufA, awp, bufA);
  // CA scores (p dead) + beta (in-place over eca)
  k_escore<<<dim3(16, 2, 64), blk, 0, stream>>>(qproj, kproj, maskw, rvec, bufP, 0);
  k_beta<<<dim3(16384), blk, 0, stream>>>(bufP, bufA);
  // value path (key dead -> xbf reused; alpha dead -> bufA becomes vT)
  k_cvt_pad<<<dim3(16384), blk, 0, stream>>>(value, xbf);
  k_proj<<<dim3(2048), blk, 0, stream>>>(xbf, wt[4], bv, kproj);
  k_build_vT<<<dim3(32, 4, 64), blk, 0, stream>>>(kproj, bufA);
  // context + output
  k_cv<<<dim3(2, 2, 64), blk, 0, stream>>>(bufP, bufA, cv_bf);
  k_out<<<dim3(8, 32), blk, 0, stream>>>(cv_bf, wt[5], bo, outp);
}

// Round 14
// 1000.193 us; speedup vs baseline: 1.0104x; 1.0104x over previous
//
#include <hip/hip_runtime.h>

// ---------------------------------------------------------------------------
// MoChA monotonic chunkwise attention. B=16, K=2000(pad 2048), Q=256, D=1024,
// H=4, dk=256, W=8, SCALE=32.
// R6: mask bit-packed; LDS-transpose epilogue on all MFMA kernels.
// R10: BK=64, octet-distinct XOR staging swizzle (rule #21 both-sides).
// R13 k_scan: depth-8 chunk pipeline, ~107us (banked; structural floor after
// 8 variants: reg+sync 134 / raw-barrier 241 / 1-wave 234 / spin 246 /
// depth-1 120 / depth-3 115 / depth-8 107).
// R15 hybrid (BEST PASSING, 1008us): k_proj/k_escore 2-buffer 64KB vmcnt(8)
// (2 blocks/CU); k_cv/k_out depth-2 96KB vmcnt(16) (grids <=256 = 1/CU).
// R16 single-stash epilogue: neutral. R17 256^2 x 8-wave: CORRECTNESS RACE
// (post-timing replay divergence) - reverted; do not re-graft without the
// full verified 8-phase template and a race-screen.
// Arena 285 MiB, ws_size-guarded.
// ---------------------------------------------------------------------------

typedef __bf16 bf16x8_t __attribute__((ext_vector_type(8)));
typedef float f32x4_t __attribute__((ext_vector_type(4)));
typedef unsigned short ushort8_t __attribute__((ext_vector_type(8)));
typedef unsigned short ushort4_t __attribute__((ext_vector_type(4)));
typedef unsigned int uint4_t __attribute__((ext_vector_type(4)));

__device__ __forceinline__ unsigned short f2bf(float x) {
  unsigned int u = __builtin_bit_cast(unsigned int, x);
  u += 0x7fffu + ((u >> 16) & 1u);  // RNE
  return (unsigned short)(u >> 16);
}
__device__ __forceinline__ float bf2f(unsigned short h) {
  unsigned int u = ((unsigned int)h) << 16;
  return __builtin_bit_cast(float, u);
}

// async 16B/lane global->LDS; lds dest must be wave-uniform base (+lane*16)
__device__ __forceinline__ void gld16(const unsigned short* g, unsigned short* l) {
  __builtin_amdgcn_global_load_lds(
      (const __attribute__((address_space(1))) void*)g,
      (__attribute__((address_space(3))) void*)l, 16, 0, 0);
}

// 64-lane inclusive prefix sum, 6 DPP steps (validated R3)
__device__ __forceinline__ float wave_incl_scan(float x) {
  float v = x;
  int mv;
#define DPP_ADD(ctrl, rmask, bctrl)                                           \
  mv = __builtin_amdgcn_update_dpp(0, __builtin_bit_cast(int, v), ctrl,       \
                                   rmask, 0xf, bctrl);                        \
  v += __builtin_bit_cast(float, mv);
  DPP_ADD(0x111, 0xf, true);   // row_shr:1
  DPP_ADD(0x112, 0xf, true);   // row_shr:2
  DPP_ADD(0x114, 0xf, true);   // row_shr:4
  DPP_ADD(0x118, 0xf, true);   // row_shr:8
  DPP_ADD(0x142, 0xa, false);  // bcast15 -> rows 1,3
  DPP_ADD(0x143, 0xc, false);  // bcast31 -> rows 2,3
#undef DPP_ADD
  return v;
}

// wave max, broadcast to all lanes
__device__ __forceinline__ float wave_max_bcast(float x) {
  const float NI = -__builtin_inff();
  float v = x;
  int mv;
#define DPP_MAX(ctrl, rmask)                                                  \
  mv = __builtin_amdgcn_update_dpp(__builtin_bit_cast(int, NI),               \
                                   __builtin_bit_cast(int, v), ctrl, rmask,   \
                                   0xf, false);                               \
  v = fmaxf(v, __builtin_bit_cast(float, mv));
  DPP_MAX(0x111, 0xf) DPP_MAX(0x112, 0xf) DPP_MAX(0x114, 0xf)
  DPP_MAX(0x118, 0xf) DPP_MAX(0x142, 0xa) DPP_MAX(0x143, 0xc)
#undef DPP_MAX
  int r = __builtin_amdgcn_readlane(__builtin_bit_cast(int, v), 63);
  return __builtin_bit_cast(float, r);
}

#define WSHR1(dst, src)                                                       \
  {                                                                           \
    int _t = __builtin_amdgcn_update_dpp(0, __builtin_bit_cast(int, src),     \
                                         0x138, 0xf, 0xf, true);              \
    dst = __builtin_bit_cast(float, _t);                                      \
  }
#define WSHL1(dst, src)                                                       \
  {                                                                           \
    int _t = __builtin_amdgcn_update_dpp(0, __builtin_bit_cast(int, src),     \
                                         0x130, 0xf, 0xf, true);              \
    dst = __builtin_bit_cast(float, _t);                                      \
  }

// ---- staging helper: one 128x64 half-tile pair, 8 gld16 per wave ----------
__device__ __forceinline__ void gemm_stage(const unsigned short* Ag, long lda,
                                           const unsigned short* Bg, long ldb,
                                           int wid, unsigned short* lA,
                                           unsigned short* lB) {
#pragma unroll
  for (int r = 0; r < 4; ++r) {
    gld16(Ag + (long)(r * 8) * lda, lA + (wid * 32 + r * 8) * 64);
    gld16(Bg + (long)(r * 8) * ldb, lB + (wid * 32 + r * 8) * 64);
  }
}

// ---- shared fragment-read + MFMA for one BK=64 tile -----------------------
__device__ __forceinline__ void gemm_compute(const unsigned short* cA,
                                             const unsigned short* cB,
                                             int wm, int wn, int lr, int quad,
                                             int rs, f32x4_t acc[4][4]) {
#pragma unroll
  for (int kk = 0; kk < 2; ++kk) {
    bf16x8_t afr[4], bfr[4];
#pragma unroll
    for (int i = 0; i < 4; ++i)
      afr[i] = *(const bf16x8_t*)(cA + (wm * 64 + i * 16 + lr) * 64 +
                                  (((kk * 4 + quad) ^ rs) << 3));
#pragma unroll
    for (int j = 0; j < 4; ++j)
      bfr[j] = *(const bf16x8_t*)(cB + (wn * 64 + j * 16 + lr) * 64 +
                                  (((kk * 4 + quad) ^ rs) << 3));
#pragma unroll
    for (int i = 0; i < 4; ++i)
#pragma unroll
      for (int j = 0; j < 4; ++j)
        acc[i][j] = __builtin_amdgcn_mfma_f32_16x16x32_bf16(afr[i], bfr[j], acc[i][j], 0, 0, 0);
  }
}

// ---- R12 tile: BK=64, 1-ahead counted-vmcnt, 2 buffers (64KB) -------------
// For high-block-count kernels (k_proj/k_escore): keeps 2 blocks/CU.
__device__ __forceinline__ void gemm_bt_tile(
    const unsigned short* __restrict__ A, long lda,
    const unsigned short* __restrict__ B, long ldb, int Kd,
    char* smem, f32x4_t acc[4][4]) {
  const int tid = threadIdx.x;
  const int lane = tid & 63;
  const int wid = tid >> 6;
  const int wm = wid >> 1, wn = wid & 1;
  const int lr = lane & 15, quad = lane >> 4;
  const int srow = wid * 32 + (lane >> 3);          // base staging row
  const int scol = ((lane & 7) ^ (lane >> 3)) * 8;  // pre-swizzled src granule
  const int rs = lr & 7;                            // read-side XOR key
  const unsigned short* Ag = A + (long)srow * lda + scol;
  const unsigned short* Bg = B + (long)srow * ldb + scol;
  const int nt = Kd >> 6;
  gemm_stage(Ag, lda, Bg, ldb, wid,
             (unsigned short*)smem, (unsigned short*)(smem + 16384));
  for (int t = 0; t < nt; ++t) {
    const unsigned short* cA = (const unsigned short*)(smem + (t & 1) * 32768);
    const unsigned short* cB = (const unsigned short*)(smem + (t & 1) * 32768 + 16384);
    if (t + 1 < nt) {
      unsigned short* nA = (unsigned short*)(smem + ((t + 1) & 1) * 32768);
      unsigned short* nB = (unsigned short*)(smem + ((t + 1) & 1) * 32768 + 16384);
      gemm_stage(Ag + (t + 1) * 64, lda, Bg + (t + 1) * 64, ldb, wid, nA, nB);
      asm volatile("s_waitcnt vmcnt(8)" ::: "memory");
    } else {
      asm volatile("s_waitcnt vmcnt(0)" ::: "memory");
    }
    __builtin_amdgcn_s_barrier();
    asm volatile("" ::: "memory");
    gemm_compute(cA, cB, wm, wn, lr, quad, rs, acc);
    asm volatile("" ::: "memory");
    __builtin_amdgcn_s_barrier();
  }
}

// ---- depth-2 tile: BK=64, 2-ahead counted-vmcnt, 3 buffers (96KB) ---------
// ONLY for grids <= 256 blocks (1 block/CU regardless of LDS): k_cv, k_out.
__device__ __forceinline__ void gemm_bt_tile_d2(
    const unsigned short* __restrict__ A, long lda,
    const unsigned short* __restrict__ B, long ldb, int Kd,
    char* smem, f32x4_t acc[4][4]) {
  const int tid = threadIdx.x;
  const int lane = tid & 63;
  const int wid = tid >> 6;
  const int wm = wid >> 1, wn = wid & 1;
  const int lr = lane & 15, quad = lane >> 4;
  const int srow = wid * 32 + (lane >> 3);
  const int scol = ((lane & 7) ^ (lane >> 3)) * 8;
  const int rs = lr & 7;
  const unsigned short* Ag = A + (long)srow * lda + scol;
  const unsigned short* Bg = B + (long)srow * ldb + scol;
  const int nt = Kd >> 6;
  gemm_stage(Ag, lda, Bg, ldb, wid,
             (unsigned short*)smem, (unsigned short*)(smem + 16384));
  gemm_stage(Ag + 64, lda, Bg + 64, ldb, wid,
             (unsigned short*)(smem + 32768), (unsigned short*)(smem + 49152));
  for (int t = 0; t < nt; ++t) {
    int bc = t % 3;
    const unsigned short* cA = (const unsigned short*)(smem + bc * 32768);
    const unsigned short* cB = (const unsigned short*)(smem + bc * 32768 + 16384);
    if (t + 2 < nt) {
      int bn = (t + 2) % 3;
      unsigned short* nA = (unsigned short*)(smem + bn * 32768);
      unsigned short* nB = (unsigned short*)(smem + bn * 32768 + 16384);
      gemm_stage(Ag + (t + 2) * 64, lda, Bg + (t + 2) * 64, ldb, wid, nA, nB);
      asm volatile("s_waitcnt vmcnt(16)" ::: "memory");
    } else if (t + 1 < nt) {
      asm volatile("s_waitcnt vmcnt(8)" ::: "memory");
    } else {
      asm volatile("s_waitcnt vmcnt(0)" ::: "memory");
    }
    __builtin_amdgcn_s_barrier();
    asm volatile("" ::: "memory");
    gemm_compute(cA, cB, wm, wn, lr, quad, rs, acc);
    asm volatile("" ::: "memory");
    __builtin_amdgcn_s_barrier();
  }
}

#define EPILOGUE_IDX()                                          \
  const int tid = threadIdx.x, lane = tid & 63, wid = tid >> 6; \
  const int wm = wid >> 1, wn = wid & 1, lr = lane & 15, quad = lane >> 4;

#define ACC_INIT()                              \
  f32x4_t acc[4][4];                            \
  _Pragma("unroll") for (int i = 0; i < 4; ++i) \
  _Pragma("unroll") for (int j = 0; j < 4; ++j) \
  _Pragma("unroll") for (int r = 0; r < 4; ++r) acc[i][j][r] = 0.f;

#define GEMM_SMEM2()                                        \
  __shared__ __attribute__((aligned(16))) char smem[65536]; \
  float* lT = (float*)smem;

#define GEMM_SMEM3()                                        \
  __shared__ __attribute__((aligned(16))) char smem[98304]; \
  float* lT = (float*)smem;

// ---- transpose-epilogue helpers -------------------------------------------
// Pass i stages the 32x128 f32 quadrant into swizzled LDS; reader thread t
// owns local row t>>3 and granules col4=(t&7)+8m. Swizzle: granule ^= row&7
// -> writes 2-way (free), f32x4 reads octet-distinct (conflict-free).
__device__ __forceinline__ void epi_stash(float* lT, f32x4_t (&acc)[4][4],
                                          int i, int wm, int wn, int lr, int quad) {
#pragma unroll
  for (int j = 0; j < 4; ++j) {
    int lcol = wn * 64 + j * 16 + lr;
#pragma unroll
    for (int r = 0; r < 4; ++r) {
      int lrow = wm * 16 + quad * 4 + r;
      lT[lrow * 128 + (((lcol >> 2) ^ (lrow & 7)) << 2) + (lcol & 3)] = acc[i][j][r];
    }
  }
}
__device__ __forceinline__ f32x4_t epi_read(const float* lT, int rloc, int col4) {
  return *(const f32x4_t*)&lT[rloc * 128 + ((col4 ^ (rloc & 7)) << 2)];
}

// ---- projection: C_bf16 = bf16(A_bf @ Wt^T + bias), N=1024, 1D swizzled ---
__global__ __launch_bounds__(256) void k_proj(const unsigned short* __restrict__ A,
                                              const unsigned short* __restrict__ Wt,
                                              const float* __restrict__ bias,
                                              unsigned short* __restrict__ C) {
  GEMM_SMEM2();
  ACC_INIT();
  int flat = blockIdx.x;
  int mb = (flat >> 6) * 8 + (flat & 7);
  int nb = (flat >> 3) & 7;
  const unsigned short* Ab = A + (long)mb * 128 * 1024;
  const unsigned short* Bb = Wt + (long)nb * 128 * 1024;
  gemm_bt_tile(Ab, 1024, Bb, 1024, 1024, smem, acc);
  EPILOGUE_IDX();
  (void)lane;
  long mbase = (long)mb * 128;
  int nbase = nb * 128;
  const int rloc = tid >> 3, c7 = tid & 7;
#pragma unroll
  for (int i = 0; i < 4; ++i) {
    __syncthreads();
    epi_stash(lT, acc, i, wm, wn, lr, quad);
    __syncthreads();
    long mg = mbase + (rloc >> 4) * 64 + i * 16 + (rloc & 15);
    unsigned short* crow = C + mg * 1024 + nbase;
    const float* brow = bias + nbase;
#pragma unroll
    for (int m = 0; m < 4; ++m) {
      int col4 = c7 + 8 * m;
      f32x4_t v = epi_read(lT, rloc, col4);
      f32x4_t bv = *(const f32x4_t*)&brow[col4 * 4];
      ushort4_t o;
#pragma unroll
      for (int z = 0; z < 4; ++z) o[z] = f2bf(v[z] + bv[z]);
      *(ushort4_t*)(crow + col4 * 4) = o;
    }
  }
}

// ---- mask int32 [16][256][2000] -> packed bits [16*256][64 words] ---------
__global__ __launch_bounds__(256) void k_maskpack(const int* __restrict__ mask,
                                                  unsigned int* __restrict__ mw) {
  int lane = threadIdx.x & 63, wid = threadIdx.x >> 6;
  int row = blockIdx.x * 4 + wid;  // 0..4095 = b*256+q
  const int* mp = mask + (long)row * 2000;
  unsigned int* op = mw + (long)row * 64;
  for (int c = 0; c < 32; ++c) {
    int k = c * 64 + lane;
    int v = (k < 2000) ? mp[k] : 0;
    unsigned long long b = __ballot(v != 0);
    if (lane == 0) {
      op[c * 2] = (unsigned int)b;
      op[c * 2 + 1] = (unsigned int)(b >> 32);
    }
  }
}

// ---- attention scores -> bf16. kproj padded to 2048 rows/batch ------------
__global__ __launch_bounds__(256) void k_escore(const unsigned short* __restrict__ qproj,
                                                const unsigned short* __restrict__ kproj,
                                                const unsigned int* __restrict__ maskw,
                                                const float* __restrict__ rptr,
                                                unsigned short* __restrict__ outp, int is_ma) {
  GEMM_SMEM2();
  ACC_INIT();
  int bz = blockIdx.z, b = bz >> 2, h = bz & 3;
  int nrow0 = blockIdx.x * 128;
  const unsigned short* Ab = qproj + ((long)b * 256 + blockIdx.y * 128) * 1024 + h * 256;
  const unsigned short* Bb = kproj + ((long)b * 2048 + nrow0) * 1024 + h * 256;
  gemm_bt_tile(Ab, 1024, Bb, 1024, 256, smem, acc);
  float rv = is_ma ? rptr[0] : 0.f;
  EPILOGUE_IDX();
  (void)lane;
  const int rloc = tid >> 3, c7 = tid & 7;
#pragma unroll
  for (int i = 0; i < 4; ++i) {
    __syncthreads();
    epi_stash(lT, acc, i, wm, wn, lr, quad);
    __syncthreads();
    int qg = blockIdx.y * 128 + (rloc >> 4) * 64 + i * 16 + (rloc & 15);
    uint4_t mw4 = *(const uint4_t*)(maskw + (((long)b * 256 + qg) << 6) + (nrow0 >> 5));
    unsigned short* orow = outp + ((long)bz * 256 + qg) * 2048 + nrow0;
#pragma unroll
    for (int m = 0; m < 4; ++m) {
      int col4 = c7 + 8 * m;
      f32x4_t v = epi_read(lT, rloc, col4);
      unsigned int bits = (mw4[m] >> (4 * c7)) & 0xFu;
      ushort4_t o;
#pragma unroll
      for (int z = 0; z < 4; ++z) {
        float e = v[z] * 0.03125f;
        bool valid = (bits >> z) & 1u;
        float ov;
        if (is_ma)
          ov = valid ? (1.f / (1.f + __expf(-(e + rv)))) : 0.f;
        else
          ov = valid ? e : -1e9f;
        o[z] = f2bf(ov);
      }
      *(ushort4_t*)(orow + col4 * 4) = o;
    }
  }
}

// ---- cp = exp(exclusive_cumsum_k(log(clip(1-p)))), bf16, parallel ---------
__global__ __launch_bounds__(256) void k_cp(const unsigned short* __restrict__ p,
                                            unsigned short* __restrict__ cp) {
  __shared__ float wsum[4];
  long base = (long)blockIdx.x * 2048;
  int tid = threadIdx.x, lane = tid & 63, wid = tid >> 6;
  ushort8_t p8 = *(const ushort8_t*)(p + base + tid * 8);
  float lex[8], s1 = 0.f;
#pragma unroll
  for (int i = 0; i < 8; ++i) {
    float om = fminf(fmaxf(1.f - bf2f((unsigned short)p8[i]), 1e-6f), 1.f);
    lex[i] = s1;
    s1 += __logf(om);
  }
  float incl = wave_incl_scan(s1);
  if (lane == 63) wsum[wid] = incl;
  __syncthreads();
  float off = incl - s1;
  if (wid > 0) off += wsum[0];
  if (wid > 1) off += wsum[1];
  if (wid > 2) off += wsum[2];
  ushort8_t o;
#pragma unroll
  for (int i = 0; i < 8; ++i) o[i] = f2bf(__expf(off + lex[i]));
  *(ushort8_t*)(cp + base + tid * 8) = o;
}

// ---- sequential scan over q; cp MAY ALIAS alpha (row read before write) ---
// R13: depth-8 chunk pipeline, uniform schedule (banked at ~107us).
__global__ __launch_bounds__(256) void k_scan(const unsigned short* __restrict__ p,
                                              const unsigned short* cp,
                                              const float* __restrict__ awp,
                                              unsigned short* alpha) {
  __shared__ unsigned short lsp[8][2][2048];
  __shared__ unsigned short lsc[8][2][2048];
  __shared__ float wsum[2][4];
  int bh = blockIdx.x;
  int tid = threadIdx.x, lane = tid & 63, w = tid >> 6;
  long base = (long)bh * 256 * 2048;
  float aw[8];
  const float* ap = awp + (long)bh * 2000;
#pragma unroll
  for (int i = 0; i < 8; ++i) {
    int k = tid * 8 + i;
    aw[i] = (k < 2000) ? ap[k] : 0.f;
  }
  const unsigned short* pg = p + base;
  const unsigned short* cg = cp + base;
  unsigned short* ag = alpha + base;
  const int sa = w >> 1;  // 0 -> stage p, 1 -> stage cp
  const int sr = w & 1;   // chunk-local row this wave stages
  const unsigned short* sbase = (sa ? cg : pg) + (long)sr * 2048 + lane * 8;
#define STAGE(c, b)                                                           \
  {                                                                           \
    const unsigned short* _src = sbase + (long)(c) * 2 * 2048;                \
    unsigned short* _dst = sa ? &lsc[b][sr][0] : &lsp[b][sr][0];              \
    _Pragma("unroll") for (int _q = 0; _q < 4; ++_q)                          \
        gld16(_src + _q * 512, _dst + _q * 512);                              \
  }
#pragma unroll
  for (int c0 = 0; c0 < 7; ++c0) STAGE(c0, c0);
  for (int c = 0; c < 128; ++c) {
    const int b = c & 7;
    {
      int cc = c + 7;
      int bb = cc & 7;
      if (cc > 127) cc = 127;  // tail: re-stage last chunk into dead buffer
      STAGE(cc, bb);
    }
    asm volatile("s_waitcnt vmcnt(28)" ::: "memory");
    __builtin_amdgcn_s_barrier();
    asm volatile("" ::: "memory");
#pragma unroll
    for (int cr = 0; cr < 2; ++cr) {
      const int q = c * 2 + cr;
      ushort8_t p8 = *(const ushort8_t*)&lsp[b][cr][tid * 8];
      ushort8_t c8 = *(const ushort8_t*)&lsc[b][cr][tid * 8];
      float pc[8], rd[8];
#pragma unroll
      for (int i = 0; i < 8; ++i) {
        float pv = bf2f((unsigned short)p8[i]);
        float cv = bf2f((unsigned short)c8[i]);
        pc[i] = pv * cv;
        rd[i] = __builtin_amdgcn_rcpf(fminf(fmaxf(cv, 1e-6f), 1.f));
      }
      float t[8], s1 = 0.f;
#pragma unroll
      for (int i = 0; i < 8; ++i) {
        s1 = fmaf(aw[i], rd[i], s1);
        t[i] = s1;
      }
      float incl = wave_incl_scan(s1);
      if (lane == 63) wsum[q & 1][w] = incl;
      asm volatile("s_waitcnt lgkmcnt(0)" ::: "memory");
      __builtin_amdgcn_s_barrier();
      asm volatile("" ::: "memory");
      float off = incl - s1;
      if (w > 0) off += wsum[q & 1][0];
      if (w > 1) off += wsum[q & 1][1];
      if (w > 2) off += wsum[q & 1][2];
      ushort8_t o;
#pragma unroll
      for (int i = 0; i < 8; ++i) {
        aw[i] = pc[i] * (t[i] + off);
        o[i] = f2bf(aw[i]);
      }
      *(ushort8_t*)(ag + (long)q * 2048 + tid * 8) = o;
    }
  }
#undef STAGE
}

// ---- beta = se * movsum_fwd7(alpha / movsum_back7(se)); register/DPP ------
__global__ __launch_bounds__(256) void k_beta(unsigned short* eca,
                                              const unsigned short* __restrict__ alpha) {
  __shared__ float red[4];
  __shared__ float edgeB[4][8];
  __shared__ float edgeF[4][8];
  long base = (long)blockIdx.x * 2048 + threadIdx.x * 8;
  int tid = threadIdx.x, lane = tid & 63, wid = tid >> 6;
  (void)tid;
  ushort8_t u8 = *(const ushort8_t*)(eca + base);
  ushort8_t a8 = *(const ushort8_t*)(alpha + base);
  float u[8], a[8];
#pragma unroll
  for (int i = 0; i < 8; ++i) {
    u[i] = bf2f((unsigned short)u8[i]);
    a[i] = bf2f((unsigned short)a8[i]);
  }
  // block max
  float m = u[0];
#pragma unroll
  for (int i = 1; i < 8; ++i) m = fmaxf(m, u[i]);
  m = wave_max_bcast(m);
  if (lane == 0) red[wid] = m;
  __syncthreads();
  m = fmaxf(fmaxf(red[0], red[1]), fmaxf(red[2], red[3]));
  // se + local prefix lp
  float se[8], lp[8];
  float s = 0.f;
#pragma unroll
  for (int i = 0; i < 8; ++i) {
    se[i] = fmaxf(__expf(u[i] - m), 1e-5f);
    s += se[i];
    lp[i] = s;
  }
  // prev-lane lp (wave_shr:1), cross-wave patch via LDS
  float plp[8];
#pragma unroll
  for (int i = 0; i < 8; ++i) WSHR1(plp[i], lp[i]);
  if (lane == 63) {
#pragma unroll
    for (int i = 0; i < 8; ++i) edgeB[wid][i] = lp[i];
  }
  __syncthreads();
  if (lane == 0 && wid > 0) {
#pragma unroll
    for (int i = 0; i < 8; ++i) plp[i] = edgeB[wid - 1][i];
  }
  // msb = lp[i] + prevTotal - prevlp[i]; sra = a/msb; local prefix lf
  float sra[8], lf[8];
  s = 0.f;
#pragma unroll
  for (int i = 0; i < 8; ++i) {
    float msb = lp[i] + plp[7] - plp[i];
    sra[i] = a[i] * __builtin_amdgcn_rcpf(msb);
    s += sra[i];
    lf[i] = s;
  }
  // next-lane lf (wave_shl:1), cross-wave patch
  float nlf[8];
#pragma unroll
  for (int i = 0; i < 8; ++i) WSHL1(nlf[i], lf[i]);
  if (lane == 0) {
#pragma unroll
    for (int i = 0; i < 8; ++i) edgeF[wid][i] = lf[i];
  }
  __syncthreads();
  if (lane == 63 && wid < 3) {
#pragma unroll
    for (int i = 0; i < 8; ++i) nlf[i] = edgeF[wid + 1][i];
  }
  ushort8_t o;
#pragma unroll
  for (int i = 0; i < 8; ++i) {
    float own = lf[7] - (i ? lf[i - 1] : 0.f);
    float nxt = i ? nlf[i - 1] : 0.f;
    o[i] = f2bf(se[i] * (own + nxt));
  }
  *(ushort8_t*)(eca + base) = o;
}

// ---- vT[bz][d][k] = vproj[(b*2048+k)*1024 + h*256+d] ----------------------
__global__ __launch_bounds__(256) void k_build_vT(const unsigned short* __restrict__ v,
                                                  unsigned short* __restrict__ vT) {
  __shared__ unsigned short t[64][68];
  int bz = blockIdx.z, b = bz >> 2, h = bz & 3;
  int k0 = blockIdx.x * 64, d0 = blockIdx.y * 64;
  int tx = threadIdx.x & 63, tg = threadIdx.x >> 6;
#pragma unroll
  for (int i = 0; i < 16; ++i) {
    int kk = tg * 16 + i;
    t[kk][tx] = v[((long)(b * 2048 + k0 + kk)) * 1024 + h * 256 + d0 + tx];
  }
  __syncthreads();
#pragma unroll
  for (int i = 0; i < 16; ++i) {
    int dd = tg * 16 + i;
    vT[((long)bz * 256 + d0 + dd) * 2048 + k0 + tx] = t[tx][dd];
  }
}

// ---- cv = beta @ v (per bz: 256x2048 @ 2048x256), bf16 out ----------------
__global__ __launch_bounds__(256) void k_cv(const unsigned short* __restrict__ beta,
                                            const unsigned short* __restrict__ vT,
                                            unsigned short* __restrict__ cv) {
  GEMM_SMEM3();
  ACC_INIT();
  int bz = blockIdx.z, b = bz >> 2, h = bz & 3;
  const unsigned short* Ab = beta + (long)bz * 256 * 2048 + (long)blockIdx.y * 128 * 2048;
  const unsigned short* Bb = vT + (long)bz * 256 * 2048 + (long)blockIdx.x * 128 * 2048;
  gemm_bt_tile_d2(Ab, 2048, Bb, 2048, 2048, smem, acc);
  EPILOGUE_IDX();
  (void)lane;
  const int rloc = tid >> 3, c7 = tid & 7;
#pragma unroll
  for (int i = 0; i < 4; ++i) {
    __syncthreads();
    epi_stash(lT, acc, i, wm, wn, lr, quad);
    __syncthreads();
    long mg = (long)b * 256 + blockIdx.y * 128 + (rloc >> 4) * 64 + i * 16 + (rloc & 15);
    unsigned short* crow = cv + mg * 1024 + h * 256 + blockIdx.x * 128;
#pragma unroll
    for (int m = 0; m < 4; ++m) {
      int col4 = c7 + 8 * m;
      f32x4_t v = epi_read(lT, rloc, col4);
      ushort4_t o;
#pragma unroll
      for (int z = 0; z < 4; ++z) o[z] = f2bf(v[z]);
      *(ushort4_t*)(crow + col4 * 4) = o;
    }
  }
}

// ---- out = cv @ WoT^T + bo, fp32, M=4096 N=1024 ---------------------------
__global__ __launch_bounds__(256) void k_out(const unsigned short* __restrict__ cv,
                                             const unsigned short* __restrict__ WoT,
                                             const float* __restrict__ bo,
                                             float* __restrict__ outp) {
  GEMM_SMEM3();
  ACC_INIT();
  const unsigned short* Ab = cv + (long)blockIdx.y * 128 * 1024;
  const unsigned short* Bb = WoT + (long)blockIdx.x * 128 * 1024;
  gemm_bt_tile_d2(Ab, 1024, Bb, 1024, 1024, smem, acc);
  EPILOGUE_IDX();
  (void)lane;
  const int rloc = tid >> 3, c7 = tid & 7;
#pragma unroll
  for (int i = 0; i < 4; ++i) {
    __syncthreads();
    epi_stash(lT, acc, i, wm, wn, lr, quad);
    __syncthreads();
    long mg = (long)blockIdx.y * 128 + (rloc >> 4) * 64 + i * 16 + (rloc & 15);
    float* orow = outp + mg * 1024 + blockIdx.x * 128;
    const float* brow = bo + blockIdx.x * 128;
#pragma unroll
    for (int m = 0; m < 4; ++m) {
      int col4 = c7 + 8 * m;
      f32x4_t v = epi_read(lT, rloc, col4);
      f32x4_t bv = *(const f32x4_t*)&brow[col4 * 4];
      *(f32x4_t*)&orow[col4 * 4] = v + bv;
    }
  }
}

// ---- W(1024x1024 f32) -> Wt bf16, Wt[n][d] = W[d][n] ----------------------
__global__ __launch_bounds__(256) void k_twT(const float* __restrict__ W,
                                             unsigned short* __restrict__ Wt) {
  __shared__ float t[32][33];
  int bx = blockIdx.x, by = blockIdx.y;
  int lx = threadIdx.x & 31, ly = threadIdx.x >> 5;
#pragma unroll
  for (int r = 0; r < 4; ++r)
    t[ly + 8 * r][lx] = W[((long)(by * 32 + ly + 8 * r)) * 1024 + bx * 32 + lx];
  __syncthreads();
#pragma unroll
  for (int r = 0; r < 4; ++r)
    Wt[((long)(bx * 32 + ly + 8 * r)) * 1024 + by * 32 + lx] = f2bf(t[lx][ly + 8 * r]);
}

// ---- fp32 [16][2000][1024] -> bf16 [16][2048][1024], pads zero ------------
__global__ __launch_bounds__(256) void k_cvt_pad(const float* __restrict__ src,
                                                 unsigned short* __restrict__ dst) {
  long idx = (long)blockIdx.x * 256 + threadIdx.x;  // 8-elem chunks
  int b = (int)(idx >> 18);                         // 262144 chunks / batch
  int rem = (int)(idx & 262143);
  int row = rem >> 7;
  int c8 = rem & 127;
  ushort8_t o;
  if (row < 2000) {
    const float* sp = src + ((long)(b * 2000 + row)) * 1024 + c8 * 8;
    float4 f0 = *(const float4*)sp;
    float4 f1 = *(const float4*)(sp + 4);
    o[0] = f2bf(f0.x); o[1] = f2bf(f0.y); o[2] = f2bf(f0.z); o[3] = f2bf(f0.w);
    o[4] = f2bf(f1.x); o[5] = f2bf(f1.y); o[6] = f2bf(f1.z); o[7] = f2bf(f1.w);
  } else {
#pragma unroll
    for (int z = 0; z < 8; ++z) o[z] = 0;
  }
  *(ushort8_t*)(dst + idx * 8) = o;
}

// ---- fp32 -> bf16 plain (query) -------------------------------------------
__global__ __launch_bounds__(256) void k_cvt(const float* __restrict__ src,
                                             unsigned short* __restrict__ dst) {
  long idx = (long)blockIdx.x * 256 + threadIdx.x;
  const float* sp = src + idx * 8;
  float4 f0 = *(const float4*)sp;
  float4 f1 = *(const float4*)(sp + 4);
  ushort8_t o;
  o[0] = f2bf(f0.x); o[1] = f2bf(f0.y); o[2] = f2bf(f0.z); o[3] = f2bf(f0.w);
  o[4] = f2bf(f1.x); o[5] = f2bf(f1.y); o[6] = f2bf(f1.z); o[7] = f2bf(f1.w);
  *(ushort8_t*)(dst + idx * 8) = o;
}

// ---------------------------------------------------------------------------
extern "C" void kernel_launch(void* const* d_in, const int* in_sizes, int n_in,
                              void* d_out, int out_size, void* d_ws, size_t ws_size,
                              hipStream_t stream) {
  const float* key = (const float*)d_in[0];
  const float* value = (const float*)d_in[1];
  const float* query = (const float*)d_in[2];
  const int* mask = (const int*)d_in[3];
  const float* awp = (const float*)d_in[4];
  const float* Wk_ma = (const float*)d_in[5];
  const float* bk_ma = (const float*)d_in[6];
  const float* Wq_ma = (const float*)d_in[7];
  const float* bq_ma = (const float*)d_in[8];
  const float* rvec = (const float*)d_in[9];
  const float* Wk_ca = (const float*)d_in[10];
  const float* bk_ca = (const float*)d_in[11];
  const float* Wq_ca = (const float*)d_in[12];
  const float* bq_ca = (const float*)d_in[13];
  const float* Wv = (const float*)d_in[14];
  const float* bv = (const float*)d_in[15];
  const float* Wo = (const float*)d_in[16];
  const float* bo = (const float*)d_in[17];
  float* outp = (float*)d_out;
  (void)in_sizes; (void)n_in; (void)out_size;

  // arena, 285 MiB
  char* ws = (char*)d_ws;
  size_t off = 0;
  auto alloc = [&](size_t bytes) {
    void* pp = ws + off;
    off += (bytes + 255) & ~(size_t)255;
    return pp;
  };
  unsigned short* wt[6];
  for (int i = 0; i < 6; ++i) wt[i] = (unsigned short*)alloc(1024L * 1024 * 2);
  unsigned short* xbf = (unsigned short*)alloc(16L * 2048 * 1024 * 2);   // key_bf -> value_bf
  unsigned short* qbf = (unsigned short*)alloc(4096L * 1024 * 2);        // query_bf -> cv
  unsigned short* kproj = (unsigned short*)alloc(16L * 2048 * 1024 * 2); // k_ma -> k_ca -> v
  unsigned short* qproj = (unsigned short*)alloc(4096L * 1024 * 2);      // q_ma -> q_ca
  unsigned short* bufP = (unsigned short*)alloc(64L * 256 * 2048 * 2);   // p -> eca -> beta
  unsigned short* bufA = (unsigned short*)alloc(64L * 256 * 2048 * 2);   // cp -> alpha -> vT
  unsigned int* maskw = (unsigned int*)alloc(4096L * 64 * 4);            // packed mask bits
  if (ws_size < off) return;  // fail via absmax, not a fault
  unsigned short* cv_bf = qbf;

  dim3 blk(256);
  // weights + input conversion
  k_twT<<<dim3(32, 32), blk, 0, stream>>>(Wk_ma, wt[0]);
  k_twT<<<dim3(32, 32), blk, 0, stream>>>(Wq_ma, wt[1]);
  k_twT<<<dim3(32, 32), blk, 0, stream>>>(Wk_ca, wt[2]);
  k_twT<<<dim3(32, 32), blk, 0, stream>>>(Wq_ca, wt[3]);
  k_twT<<<dim3(32, 32), blk, 0, stream>>>(Wv, wt[4]);
  k_twT<<<dim3(32, 32), blk, 0, stream>>>(Wo, wt[5]);
  k_maskpack<<<dim3(1024), blk, 0, stream>>>(mask, maskw);
  k_cvt_pad<<<dim3(16384), blk, 0, stream>>>(key, xbf);
  k_cvt<<<dim3(2048), blk, 0, stream>>>(query, qbf);
  // MA path
  k_proj<<<dim3(2048), blk, 0, stream>>>(xbf, wt[0], bk_ma, kproj);
  k_proj<<<dim3(256), blk, 0, stream>>>(qbf, wt[1], bq_ma, qproj);
  k_escore<<<dim3(16, 2, 64), blk, 0, stream>>>(qproj, kproj, maskw, rvec, bufP, 1);
  k_cp<<<dim3(16384), blk, 0, stream>>>(bufP, bufA);
  // CA projections (k_ma/q_ma dead; cp lives in bufA)
  k_proj<<<dim3(2048), blk, 0, stream>>>(xbf, wt[2], bk_ca, kproj);
  k_proj<<<dim3(256), blk, 0, stream>>>(qbf, wt[3], bq_ca, qproj);
  // scan: alpha overwrites cp row-by-row (read-before-write)
  k_scan<<<dim3(64), blk, 0, stream>>>(bufP, bufA, awp, bufA);
  // CA scores (p dead) + beta (in-place over eca)
  k_escore<<<dim3(16, 2, 64), blk, 0, stream>>>(qproj, kproj, maskw, rvec, bufP, 0);
  k_beta<<<dim3(16384), blk, 0, stream>>>(bufP, bufA);
  // value path (key dead -> xbf reused; alpha dead -> bufA becomes vT)
  k_cvt_pad<<<dim3(16384), blk, 0, stream>>>(value, xbf);
  k_proj<<<dim3(2048), blk, 0, stream>>>(xbf, wt[4], bv, kproj);
  k_build_vT<<<dim3(32, 4, 64), blk, 0, stream>>>(kproj, bufA);
  // context + output
  k_cv<<<dim3(2, 2, 64), blk, 0, stream>>>(bufP, bufA, cv_bf);
  k_out<<<dim3(8, 32), blk, 0, stream>>>(cv_bf, wt[5], bo, outp);
}

// Round 15
// 986.601 us; speedup vs baseline: 1.0243x; 1.0138x over previous
//
#include <hip/hip_runtime.h>

// ---------------------------------------------------------------------------
// MoChA monotonic chunkwise attention. B=16, K=2000(pad 2048), Q=256, D=1024,
// H=4, dk=256, W=8, SCALE=32.
// R6: mask bit-packed; LDS-transpose epilogue on all MFMA kernels.
// R10: BK=64, octet-distinct XOR staging swizzle (rule #21 both-sides).
// R13 k_scan: depth-8 chunk pipeline, ~107us (banked; structural floor after
// 8 variants). R15 hybrid: k_proj/k_escore 2-buffer 64KB vmcnt(8) (2/CU);
// k_cv/k_out depth-2 96KB vmcnt(16) (grids <=256 = 1/CU). R16 neutral.
// R17 256^2 x 8-wave: CORRECTNESS RACE (replay divergence) - do not re-graft
// without the full verified 8-phase template + race-screen.
// R19 (safe harvest): (1) six k_twT launches batched into one k_twT6 (wt
// arena slots contiguous -> base + z*1M elements); (2) q-proj (grid 256 =
// exactly 1 block/CU) moved to the depth-2 96KB path (same occupancy
// argument as k_cv/k_out: LDS can't reduce residency at 1 block/CU).
// Arena 285 MiB, ws_size-guarded.
// ---------------------------------------------------------------------------

typedef __bf16 bf16x8_t __attribute__((ext_vector_type(8)));
typedef float f32x4_t __attribute__((ext_vector_type(4)));
typedef unsigned short ushort8_t __attribute__((ext_vector_type(8)));
typedef unsigned short ushort4_t __attribute__((ext_vector_type(4)));
typedef unsigned int uint4_t __attribute__((ext_vector_type(4)));

__device__ __forceinline__ unsigned short f2bf(float x) {
  unsigned int u = __builtin_bit_cast(unsigned int, x);
  u += 0x7fffu + ((u >> 16) & 1u);  // RNE
  return (unsigned short)(u >> 16);
}
__device__ __forceinline__ float bf2f(unsigned short h) {
  unsigned int u = ((unsigned int)h) << 16;
  return __builtin_bit_cast(float, u);
}

// async 16B/lane global->LDS; lds dest must be wave-uniform base (+lane*16)
__device__ __forceinline__ void gld16(const unsigned short* g, unsigned short* l) {
  __builtin_amdgcn_global_load_lds(
      (const __attribute__((address_space(1))) void*)g,
      (__attribute__((address_space(3))) void*)l, 16, 0, 0);
}

// 64-lane inclusive prefix sum, 6 DPP steps (validated R3)
__device__ __forceinline__ float wave_incl_scan(float x) {
  float v = x;
  int mv;
#define DPP_ADD(ctrl, rmask, bctrl)                                           \
  mv = __builtin_amdgcn_update_dpp(0, __builtin_bit_cast(int, v), ctrl,       \
                                   rmask, 0xf, bctrl);                        \
  v += __builtin_bit_cast(float, mv);
  DPP_ADD(0x111, 0xf, true);   // row_shr:1
  DPP_ADD(0x112, 0xf, true);   // row_shr:2
  DPP_ADD(0x114, 0xf, true);   // row_shr:4
  DPP_ADD(0x118, 0xf, true);   // row_shr:8
  DPP_ADD(0x142, 0xa, false);  // bcast15 -> rows 1,3
  DPP_ADD(0x143, 0xc, false);  // bcast31 -> rows 2,3
#undef DPP_ADD
  return v;
}

// wave max, broadcast to all lanes
__device__ __forceinline__ float wave_max_bcast(float x) {
  const float NI = -__builtin_inff();
  float v = x;
  int mv;
#define DPP_MAX(ctrl, rmask)                                                  \
  mv = __builtin_amdgcn_update_dpp(__builtin_bit_cast(int, NI),               \
                                   __builtin_bit_cast(int, v), ctrl, rmask,   \
                                   0xf, false);                               \
  v = fmaxf(v, __builtin_bit_cast(float, mv));
  DPP_MAX(0x111, 0xf) DPP_MAX(0x112, 0xf) DPP_MAX(0x114, 0xf)
  DPP_MAX(0x118, 0xf) DPP_MAX(0x142, 0xa) DPP_MAX(0x143, 0xc)
#undef DPP_MAX
  int r = __builtin_amdgcn_readlane(__builtin_bit_cast(int, v), 63);
  return __builtin_bit_cast(float, r);
}

#define WSHR1(dst, src)                                                       \
  {                                                                           \
    int _t = __builtin_amdgcn_update_dpp(0, __builtin_bit_cast(int, src),     \
                                         0x138, 0xf, 0xf, true);              \
    dst = __builtin_bit_cast(float, _t);                                      \
  }
#define WSHL1(dst, src)                                                       \
  {                                                                           \
    int _t = __builtin_amdgcn_update_dpp(0, __builtin_bit_cast(int, src),     \
                                         0x130, 0xf, 0xf, true);              \
    dst = __builtin_bit_cast(float, _t);                                      \
  }

// ---- staging helper: one 128x64 half-tile pair, 8 gld16 per wave ----------
__device__ __forceinline__ void gemm_stage(const unsigned short* Ag, long lda,
                                           const unsigned short* Bg, long ldb,
                                           int wid, unsigned short* lA,
                                           unsigned short* lB) {
#pragma unroll
  for (int r = 0; r < 4; ++r) {
    gld16(Ag + (long)(r * 8) * lda, lA + (wid * 32 + r * 8) * 64);
    gld16(Bg + (long)(r * 8) * ldb, lB + (wid * 32 + r * 8) * 64);
  }
}

// ---- shared fragment-read + MFMA for one BK=64 tile -----------------------
__device__ __forceinline__ void gemm_compute(const unsigned short* cA,
                                             const unsigned short* cB,
                                             int wm, int wn, int lr, int quad,
                                             int rs, f32x4_t acc[4][4]) {
#pragma unroll
  for (int kk = 0; kk < 2; ++kk) {
    bf16x8_t afr[4], bfr[4];
#pragma unroll
    for (int i = 0; i < 4; ++i)
      afr[i] = *(const bf16x8_t*)(cA + (wm * 64 + i * 16 + lr) * 64 +
                                  (((kk * 4 + quad) ^ rs) << 3));
#pragma unroll
    for (int j = 0; j < 4; ++j)
      bfr[j] = *(const bf16x8_t*)(cB + (wn * 64 + j * 16 + lr) * 64 +
                                  (((kk * 4 + quad) ^ rs) << 3));
#pragma unroll
    for (int i = 0; i < 4; ++i)
#pragma unroll
      for (int j = 0; j < 4; ++j)
        acc[i][j] = __builtin_amdgcn_mfma_f32_16x16x32_bf16(afr[i], bfr[j], acc[i][j], 0, 0, 0);
  }
}

// ---- R12 tile: BK=64, 1-ahead counted-vmcnt, 2 buffers (64KB) -------------
// For high-block-count kernels (k_proj/k_escore): keeps 2 blocks/CU.
__device__ __forceinline__ void gemm_bt_tile(
    const unsigned short* __restrict__ A, long lda,
    const unsigned short* __restrict__ B, long ldb, int Kd,
    char* smem, f32x4_t acc[4][4]) {
  const int tid = threadIdx.x;
  const int lane = tid & 63;
  const int wid = tid >> 6;
  const int wm = wid >> 1, wn = wid & 1;
  const int lr = lane & 15, quad = lane >> 4;
  const int srow = wid * 32 + (lane >> 3);          // base staging row
  const int scol = ((lane & 7) ^ (lane >> 3)) * 8;  // pre-swizzled src granule
  const int rs = lr & 7;                            // read-side XOR key
  const unsigned short* Ag = A + (long)srow * lda + scol;
  const unsigned short* Bg = B + (long)srow * ldb + scol;
  const int nt = Kd >> 6;
  gemm_stage(Ag, lda, Bg, ldb, wid,
             (unsigned short*)smem, (unsigned short*)(smem + 16384));
  for (int t = 0; t < nt; ++t) {
    const unsigned short* cA = (const unsigned short*)(smem + (t & 1) * 32768);
    const unsigned short* cB = (const unsigned short*)(smem + (t & 1) * 32768 + 16384);
    if (t + 1 < nt) {
      unsigned short* nA = (unsigned short*)(smem + ((t + 1) & 1) * 32768);
      unsigned short* nB = (unsigned short*)(smem + ((t + 1) & 1) * 32768 + 16384);
      gemm_stage(Ag + (t + 1) * 64, lda, Bg + (t + 1) * 64, ldb, wid, nA, nB);
      asm volatile("s_waitcnt vmcnt(8)" ::: "memory");
    } else {
      asm volatile("s_waitcnt vmcnt(0)" ::: "memory");
    }
    __builtin_amdgcn_s_barrier();
    asm volatile("" ::: "memory");
    gemm_compute(cA, cB, wm, wn, lr, quad, rs, acc);
    asm volatile("" ::: "memory");
    __builtin_amdgcn_s_barrier();
  }
}

// ---- depth-2 tile: BK=64, 2-ahead counted-vmcnt, 3 buffers (96KB) ---------
// ONLY for grids <= 256 blocks (1 block/CU regardless of LDS): q-proj,
// k_cv, k_out.
__device__ __forceinline__ void gemm_bt_tile_d2(
    const unsigned short* __restrict__ A, long lda,
    const unsigned short* __restrict__ B, long ldb, int Kd,
    char* smem, f32x4_t acc[4][4]) {
  const int tid = threadIdx.x;
  const int lane = tid & 63;
  const int wid = tid >> 6;
  const int wm = wid >> 1, wn = wid & 1;
  const int lr = lane & 15, quad = lane >> 4;
  const int srow = wid * 32 + (lane >> 3);
  const int scol = ((lane & 7) ^ (lane >> 3)) * 8;
  const int rs = lr & 7;
  const unsigned short* Ag = A + (long)srow * lda + scol;
  const unsigned short* Bg = B + (long)srow * ldb + scol;
  const int nt = Kd >> 6;
  gemm_stage(Ag, lda, Bg, ldb, wid,
             (unsigned short*)smem, (unsigned short*)(smem + 16384));
  gemm_stage(Ag + 64, lda, Bg + 64, ldb, wid,
             (unsigned short*)(smem + 32768), (unsigned short*)(smem + 49152));
  for (int t = 0; t < nt; ++t) {
    int bc = t % 3;
    const unsigned short* cA = (const unsigned short*)(smem + bc * 32768);
    const unsigned short* cB = (const unsigned short*)(smem + bc * 32768 + 16384);
    if (t + 2 < nt) {
      int bn = (t + 2) % 3;
      unsigned short* nA = (unsigned short*)(smem + bn * 32768);
      unsigned short* nB = (unsigned short*)(smem + bn * 32768 + 16384);
      gemm_stage(Ag + (t + 2) * 64, lda, Bg + (t + 2) * 64, ldb, wid, nA, nB);
      asm volatile("s_waitcnt vmcnt(16)" ::: "memory");
    } else if (t + 1 < nt) {
      asm volatile("s_waitcnt vmcnt(8)" ::: "memory");
    } else {
      asm volatile("s_waitcnt vmcnt(0)" ::: "memory");
    }
    __builtin_amdgcn_s_barrier();
    asm volatile("" ::: "memory");
    gemm_compute(cA, cB, wm, wn, lr, quad, rs, acc);
    asm volatile("" ::: "memory");
    __builtin_amdgcn_s_barrier();
  }
}

#define EPILOGUE_IDX()                                          \
  const int tid = threadIdx.x, lane = tid & 63, wid = tid >> 6; \
  const int wm = wid >> 1, wn = wid & 1, lr = lane & 15, quad = lane >> 4;

#define ACC_INIT()                              \
  f32x4_t acc[4][4];                            \
  _Pragma("unroll") for (int i = 0; i < 4; ++i) \
  _Pragma("unroll") for (int j = 0; j < 4; ++j) \
  _Pragma("unroll") for (int r = 0; r < 4; ++r) acc[i][j][r] = 0.f;

#define GEMM_SMEM2()                                        \
  __shared__ __attribute__((aligned(16))) char smem[65536]; \
  float* lT = (float*)smem;

#define GEMM_SMEM3()                                        \
  __shared__ __attribute__((aligned(16))) char smem[98304]; \
  float* lT = (float*)smem;

// ---- transpose-epilogue helpers -------------------------------------------
// Pass i stages the 32x128 f32 quadrant into swizzled LDS; reader thread t
// owns local row t>>3 and granules col4=(t&7)+8m. Swizzle: granule ^= row&7
// -> writes 2-way (free), f32x4 reads octet-distinct (conflict-free).
__device__ __forceinline__ void epi_stash(float* lT, f32x4_t (&acc)[4][4],
                                          int i, int wm, int wn, int lr, int quad) {
#pragma unroll
  for (int j = 0; j < 4; ++j) {
    int lcol = wn * 64 + j * 16 + lr;
#pragma unroll
    for (int r = 0; r < 4; ++r) {
      int lrow = wm * 16 + quad * 4 + r;
      lT[lrow * 128 + (((lcol >> 2) ^ (lrow & 7)) << 2) + (lcol & 3)] = acc[i][j][r];
    }
  }
}
__device__ __forceinline__ f32x4_t epi_read(const float* lT, int rloc, int col4) {
  return *(const f32x4_t*)&lT[rloc * 128 + ((col4 ^ (rloc & 7)) << 2)];
}

// ---- projection (big, 2048-block grid): 2-buffer 64KB, 2 blocks/CU --------
__global__ __launch_bounds__(256) void k_proj(const unsigned short* __restrict__ A,
                                              const unsigned short* __restrict__ Wt,
                                              const float* __restrict__ bias,
                                              unsigned short* __restrict__ C) {
  GEMM_SMEM2();
  ACC_INIT();
  int flat = blockIdx.x;
  int mb = (flat >> 6) * 8 + (flat & 7);
  int nb = (flat >> 3) & 7;
  const unsigned short* Ab = A + (long)mb * 128 * 1024;
  const unsigned short* Bb = Wt + (long)nb * 128 * 1024;
  gemm_bt_tile(Ab, 1024, Bb, 1024, 1024, smem, acc);
  EPILOGUE_IDX();
  (void)lane;
  long mbase = (long)mb * 128;
  int nbase = nb * 128;
  const int rloc = tid >> 3, c7 = tid & 7;
#pragma unroll
  for (int i = 0; i < 4; ++i) {
    __syncthreads();
    epi_stash(lT, acc, i, wm, wn, lr, quad);
    __syncthreads();
    long mg = mbase + (rloc >> 4) * 64 + i * 16 + (rloc & 15);
    unsigned short* crow = C + mg * 1024 + nbase;
    const float* brow = bias + nbase;
#pragma unroll
    for (int m = 0; m < 4; ++m) {
      int col4 = c7 + 8 * m;
      f32x4_t v = epi_read(lT, rloc, col4);
      f32x4_t bv = *(const f32x4_t*)&brow[col4 * 4];
      ushort4_t o;
#pragma unroll
      for (int z = 0; z < 4; ++z) o[z] = f2bf(v[z] + bv[z]);
      *(ushort4_t*)(crow + col4 * 4) = o;
    }
  }
}

// ---- projection (q-proj, 256-block grid = 1 block/CU): depth-2 96KB -------
__global__ __launch_bounds__(256) void k_proj_d2(const unsigned short* __restrict__ A,
                                                 const unsigned short* __restrict__ Wt,
                                                 const float* __restrict__ bias,
                                                 unsigned short* __restrict__ C) {
  GEMM_SMEM3();
  ACC_INIT();
  int flat = blockIdx.x;
  int mb = (flat >> 6) * 8 + (flat & 7);
  int nb = (flat >> 3) & 7;
  const unsigned short* Ab = A + (long)mb * 128 * 1024;
  const unsigned short* Bb = Wt + (long)nb * 128 * 1024;
  gemm_bt_tile_d2(Ab, 1024, Bb, 1024, 1024, smem, acc);
  EPILOGUE_IDX();
  (void)lane;
  long mbase = (long)mb * 128;
  int nbase = nb * 128;
  const int rloc = tid >> 3, c7 = tid & 7;
#pragma unroll
  for (int i = 0; i < 4; ++i) {
    __syncthreads();
    epi_stash(lT, acc, i, wm, wn, lr, quad);
    __syncthreads();
    long mg = mbase + (rloc >> 4) * 64 + i * 16 + (rloc & 15);
    unsigned short* crow = C + mg * 1024 + nbase;
    const float* brow = bias + nbase;
#pragma unroll
    for (int m = 0; m < 4; ++m) {
      int col4 = c7 + 8 * m;
      f32x4_t v = epi_read(lT, rloc, col4);
      f32x4_t bv = *(const f32x4_t*)&brow[col4 * 4];
      ushort4_t o;
#pragma unroll
      for (int z = 0; z < 4; ++z) o[z] = f2bf(v[z] + bv[z]);
      *(ushort4_t*)(crow + col4 * 4) = o;
    }
  }
}

// ---- mask int32 [16][256][2000] -> packed bits [16*256][64 words] ---------
__global__ __launch_bounds__(256) void k_maskpack(const int* __restrict__ mask,
                                                  unsigned int* __restrict__ mw) {
  int lane = threadIdx.x & 63, wid = threadIdx.x >> 6;
  int row = blockIdx.x * 4 + wid;  // 0..4095 = b*256+q
  const int* mp = mask + (long)row * 2000;
  unsigned int* op = mw + (long)row * 64;
  for (int c = 0; c < 32; ++c) {
    int k = c * 64 + lane;
    int v = (k < 2000) ? mp[k] : 0;
    unsigned long long b = __ballot(v != 0);
    if (lane == 0) {
      op[c * 2] = (unsigned int)b;
      op[c * 2 + 1] = (unsigned int)(b >> 32);
    }
  }
}

// ---- attention scores -> bf16. kproj padded to 2048 rows/batch ------------
__global__ __launch_bounds__(256) void k_escore(const unsigned short* __restrict__ qproj,
                                                const unsigned short* __restrict__ kproj,
                                                const unsigned int* __restrict__ maskw,
                                                const float* __restrict__ rptr,
                                                unsigned short* __restrict__ outp, int is_ma) {
  GEMM_SMEM2();
  ACC_INIT();
  int bz = blockIdx.z, b = bz >> 2, h = bz & 3;
  int nrow0 = blockIdx.x * 128;
  const unsigned short* Ab = qproj + ((long)b * 256 + blockIdx.y * 128) * 1024 + h * 256;
  const unsigned short* Bb = kproj + ((long)b * 2048 + nrow0) * 1024 + h * 256;
  gemm_bt_tile(Ab, 1024, Bb, 1024, 256, smem, acc);
  float rv = is_ma ? rptr[0] : 0.f;
  EPILOGUE_IDX();
  (void)lane;
  const int rloc = tid >> 3, c7 = tid & 7;
#pragma unroll
  for (int i = 0; i < 4; ++i) {
    __syncthreads();
    epi_stash(lT, acc, i, wm, wn, lr, quad);
    __syncthreads();
    int qg = blockIdx.y * 128 + (rloc >> 4) * 64 + i * 16 + (rloc & 15);
    uint4_t mw4 = *(const uint4_t*)(maskw + (((long)b * 256 + qg) << 6) + (nrow0 >> 5));
    unsigned short* orow = outp + ((long)bz * 256 + qg) * 2048 + nrow0;
#pragma unroll
    for (int m = 0; m < 4; ++m) {
      int col4 = c7 + 8 * m;
      f32x4_t v = epi_read(lT, rloc, col4);
      unsigned int bits = (mw4[m] >> (4 * c7)) & 0xFu;
      ushort4_t o;
#pragma unroll
      for (int z = 0; z < 4; ++z) {
        float e = v[z] * 0.03125f;
        bool valid = (bits >> z) & 1u;
        float ov;
        if (is_ma)
          ov = valid ? (1.f / (1.f + __expf(-(e + rv)))) : 0.f;
        else
          ov = valid ? e : -1e9f;
        o[z] = f2bf(ov);
      }
      *(ushort4_t*)(orow + col4 * 4) = o;
    }
  }
}

// ---- cp = exp(exclusive_cumsum_k(log(clip(1-p)))), bf16, parallel ---------
__global__ __launch_bounds__(256) void k_cp(const unsigned short* __restrict__ p,
                                            unsigned short* __restrict__ cp) {
  __shared__ float wsum[4];
  long base = (long)blockIdx.x * 2048;
  int tid = threadIdx.x, lane = tid & 63, wid = tid >> 6;
  ushort8_t p8 = *(const ushort8_t*)(p + base + tid * 8);
  float lex[8], s1 = 0.f;
#pragma unroll
  for (int i = 0; i < 8; ++i) {
    float om = fminf(fmaxf(1.f - bf2f((unsigned short)p8[i]), 1e-6f), 1.f);
    lex[i] = s1;
    s1 += __logf(om);
  }
  float incl = wave_incl_scan(s1);
  if (lane == 63) wsum[wid] = incl;
  __syncthreads();
  float off = incl - s1;
  if (wid > 0) off += wsum[0];
  if (wid > 1) off += wsum[1];
  if (wid > 2) off += wsum[2];
  ushort8_t o;
#pragma unroll
  for (int i = 0; i < 8; ++i) o[i] = f2bf(__expf(off + lex[i]));
  *(ushort8_t*)(cp + base + tid * 8) = o;
}

// ---- sequential scan over q; cp MAY ALIAS alpha (row read before write) ---
// R13: depth-8 chunk pipeline, uniform schedule (banked at ~107us).
__global__ __launch_bounds__(256) void k_scan(const unsigned short* __restrict__ p,
                                              const unsigned short* cp,
                                              const float* __restrict__ awp,
                                              unsigned short* alpha) {
  __shared__ unsigned short lsp[8][2][2048];
  __shared__ unsigned short lsc[8][2][2048];
  __shared__ float wsum[2][4];
  int bh = blockIdx.x;
  int tid = threadIdx.x, lane = tid & 63, w = tid >> 6;
  long base = (long)bh * 256 * 2048;
  float aw[8];
  const float* ap = awp + (long)bh * 2000;
#pragma unroll
  for (int i = 0; i < 8; ++i) {
    int k = tid * 8 + i;
    aw[i] = (k < 2000) ? ap[k] : 0.f;
  }
  const unsigned short* pg = p + base;
  const unsigned short* cg = cp + base;
  unsigned short* ag = alpha + base;
  const int sa = w >> 1;  // 0 -> stage p, 1 -> stage cp
  const int sr = w & 1;   // chunk-local row this wave stages
  const unsigned short* sbase = (sa ? cg : pg) + (long)sr * 2048 + lane * 8;
#define STAGE(c, b)                                                           \
  {                                                                           \
    const unsigned short* _src = sbase + (long)(c) * 2 * 2048;                \
    unsigned short* _dst = sa ? &lsc[b][sr][0] : &lsp[b][sr][0];              \
    _Pragma("unroll") for (int _q = 0; _q < 4; ++_q)                          \
        gld16(_src + _q * 512, _dst + _q * 512);                              \
  }
#pragma unroll
  for (int c0 = 0; c0 < 7; ++c0) STAGE(c0, c0);
  for (int c = 0; c < 128; ++c) {
    const int b = c & 7;
    {
      int cc = c + 7;
      int bb = cc & 7;
      if (cc > 127) cc = 127;  // tail: re-stage last chunk into dead buffer
      STAGE(cc, bb);
    }
    asm volatile("s_waitcnt vmcnt(28)" ::: "memory");
    __builtin_amdgcn_s_barrier();
    asm volatile("" ::: "memory");
#pragma unroll
    for (int cr = 0; cr < 2; ++cr) {
      const int q = c * 2 + cr;
      ushort8_t p8 = *(const ushort8_t*)&lsp[b][cr][tid * 8];
      ushort8_t c8 = *(const ushort8_t*)&lsc[b][cr][tid * 8];
      float pc[8], rd[8];
#pragma unroll
      for (int i = 0; i < 8; ++i) {
        float pv = bf2f((unsigned short)p8[i]);
        float cv = bf2f((unsigned short)c8[i]);
        pc[i] = pv * cv;
        rd[i] = __builtin_amdgcn_rcpf(fminf(fmaxf(cv, 1e-6f), 1.f));
      }
      float t[8], s1 = 0.f;
#pragma unroll
      for (int i = 0; i < 8; ++i) {
        s1 = fmaf(aw[i], rd[i], s1);
        t[i] = s1;
      }
      float incl = wave_incl_scan(s1);
      if (lane == 63) wsum[q & 1][w] = incl;
      asm volatile("s_waitcnt lgkmcnt(0)" ::: "memory");
      __builtin_amdgcn_s_barrier();
      asm volatile("" ::: "memory");
      float off = incl - s1;
      if (w > 0) off += wsum[q & 1][0];
      if (w > 1) off += wsum[q & 1][1];
      if (w > 2) off += wsum[q & 1][2];
      ushort8_t o;
#pragma unroll
      for (int i = 0; i < 8; ++i) {
        aw[i] = pc[i] * (t[i] + off);
        o[i] = f2bf(aw[i]);
      }
      *(ushort8_t*)(ag + (long)q * 2048 + tid * 8) = o;
    }
  }
#undef STAGE
}

// ---- beta = se * movsum_fwd7(alpha / movsum_back7(se)); register/DPP ------
__global__ __launch_bounds__(256) void k_beta(unsigned short* eca,
                                              const unsigned short* __restrict__ alpha) {
  __shared__ float red[4];
  __shared__ float edgeB[4][8];
  __shared__ float edgeF[4][8];
  long base = (long)blockIdx.x * 2048 + threadIdx.x * 8;
  int tid = threadIdx.x, lane = tid & 63, wid = tid >> 6;
  (void)tid;
  ushort8_t u8 = *(const ushort8_t*)(eca + base);
  ushort8_t a8 = *(const ushort8_t*)(alpha + base);
  float u[8], a[8];
#pragma unroll
  for (int i = 0; i < 8; ++i) {
    u[i] = bf2f((unsigned short)u8[i]);
    a[i] = bf2f((unsigned short)a8[i]);
  }
  // block max
  float m = u[0];
#pragma unroll
  for (int i = 1; i < 8; ++i) m = fmaxf(m, u[i]);
  m = wave_max_bcast(m);
  if (lane == 0) red[wid] = m;
  __syncthreads();
  m = fmaxf(fmaxf(red[0], red[1]), fmaxf(red[2], red[3]));
  // se + local prefix lp
  float se[8], lp[8];
  float s = 0.f;
#pragma unroll
  for (int i = 0; i < 8; ++i) {
    se[i] = fmaxf(__expf(u[i] - m), 1e-5f);
    s += se[i];
    lp[i] = s;
  }
  // prev-lane lp (wave_shr:1), cross-wave patch via LDS
  float plp[8];
#pragma unroll
  for (int i = 0; i < 8; ++i) WSHR1(plp[i], lp[i]);
  if (lane == 63) {
#pragma unroll
    for (int i = 0; i < 8; ++i) edgeB[wid][i] = lp[i];
  }
  __syncthreads();
  if (lane == 0 && wid > 0) {
#pragma unroll
    for (int i = 0; i < 8; ++i) plp[i] = edgeB[wid - 1][i];
  }
  // msb = lp[i] + prevTotal - prevlp[i]; sra = a/msb; local prefix lf
  float sra[8], lf[8];
  s = 0.f;
#pragma unroll
  for (int i = 0; i < 8; ++i) {
    float msb = lp[i] + plp[7] - plp[i];
    sra[i] = a[i] * __builtin_amdgcn_rcpf(msb);
    s += sra[i];
    lf[i] = s;
  }
  // next-lane lf (wave_shl:1), cross-wave patch
  float nlf[8];
#pragma unroll
  for (int i = 0; i < 8; ++i) WSHL1(nlf[i], lf[i]);
  if (lane == 0) {
#pragma unroll
    for (int i = 0; i < 8; ++i) edgeF[wid][i] = lf[i];
  }
  __syncthreads();
  if (lane == 63 && wid < 3) {
#pragma unroll
    for (int i = 0; i < 8; ++i) nlf[i] = edgeF[wid + 1][i];
  }
  ushort8_t o;
#pragma unroll
  for (int i = 0; i < 8; ++i) {
    float own = lf[7] - (i ? lf[i - 1] : 0.f);
    float nxt = i ? nlf[i - 1] : 0.f;
    o[i] = f2bf(se[i] * (own + nxt));
  }
  *(ushort8_t*)(eca + base) = o;
}

// ---- vT[bz][d][k] = vproj[(b*2048+k)*1024 + h*256+d] ----------------------
__global__ __launch_bounds__(256) void k_build_vT(const unsigned short* __restrict__ v,
                                                  unsigned short* __restrict__ vT) {
  __shared__ unsigned short t[64][68];
  int bz = blockIdx.z, b = bz >> 2, h = bz & 3;
  int k0 = blockIdx.x * 64, d0 = blockIdx.y * 64;
  int tx = threadIdx.x & 63, tg = threadIdx.x >> 6;
#pragma unroll
  for (int i = 0; i < 16; ++i) {
    int kk = tg * 16 + i;
    t[kk][tx] = v[((long)(b * 2048 + k0 + kk)) * 1024 + h * 256 + d0 + tx];
  }
  __syncthreads();
#pragma unroll
  for (int i = 0; i < 16; ++i) {
    int dd = tg * 16 + i;
    vT[((long)bz * 256 + d0 + dd) * 2048 + k0 + tx] = t[tx][dd];
  }
}

// ---- cv = beta @ v (per bz: 256x2048 @ 2048x256), bf16 out ----------------
__global__ __launch_bounds__(256) void k_cv(const unsigned short* __restrict__ beta,
                                            const unsigned short* __restrict__ vT,
                                            unsigned short* __restrict__ cv) {
  GEMM_SMEM3();
  ACC_INIT();
  int bz = blockIdx.z, b = bz >> 2, h = bz & 3;
  const unsigned short* Ab = beta + (long)bz * 256 * 2048 + (long)blockIdx.y * 128 * 2048;
  const unsigned short* Bb = vT + (long)bz * 256 * 2048 + (long)blockIdx.x * 128 * 2048;
  gemm_bt_tile_d2(Ab, 2048, Bb, 2048, 2048, smem, acc);
  EPILOGUE_IDX();
  (void)lane;
  const int rloc = tid >> 3, c7 = tid & 7;
#pragma unroll
  for (int i = 0; i < 4; ++i) {
    __syncthreads();
    epi_stash(lT, acc, i, wm, wn, lr, quad);
    __syncthreads();
    long mg = (long)b * 256 + blockIdx.y * 128 + (rloc >> 4) * 64 + i * 16 + (rloc & 15);
    unsigned short* crow = cv + mg * 1024 + h * 256 + blockIdx.x * 128;
#pragma unroll
    for (int m = 0; m < 4; ++m) {
      int col4 = c7 + 8 * m;
      f32x4_t v = epi_read(lT, rloc, col4);
      ushort4_t o;
#pragma unroll
      for (int z = 0; z < 4; ++z) o[z] = f2bf(v[z]);
      *(ushort4_t*)(crow + col4 * 4) = o;
    }
  }
}

// ---- out = cv @ WoT^T + bo, fp32, M=4096 N=1024 ---------------------------
__global__ __launch_bounds__(256) void k_out(const unsigned short* __restrict__ cv,
                                             const unsigned short* __restrict__ WoT,
                                             const float* __restrict__ bo,
                                             float* __restrict__ outp) {
  GEMM_SMEM3();
  ACC_INIT();
  const unsigned short* Ab = cv + (long)blockIdx.y * 128 * 1024;
  const unsigned short* Bb = WoT + (long)blockIdx.x * 128 * 1024;
  gemm_bt_tile_d2(Ab, 1024, Bb, 1024, 1024, smem, acc);
  EPILOGUE_IDX();
  (void)lane;
  const int rloc = tid >> 3, c7 = tid & 7;
#pragma unroll
  for (int i = 0; i < 4; ++i) {
    __syncthreads();
    epi_stash(lT, acc, i, wm, wn, lr, quad);
    __syncthreads();
    long mg = (long)blockIdx.y * 128 + (rloc >> 4) * 64 + i * 16 + (rloc & 15);
    float* orow = outp + mg * 1024 + blockIdx.x * 128;
    const float* brow = bo + blockIdx.x * 128;
#pragma unroll
    for (int m = 0; m < 4; ++m) {
      int col4 = c7 + 8 * m;
      f32x4_t v = epi_read(lT, rloc, col4);
      f32x4_t bv = *(const f32x4_t*)&brow[col4 * 4];
      *(f32x4_t*)&orow[col4 * 4] = v + bv;
    }
  }
}

// ---- 6x W(1024x1024 f32) -> Wt bf16 in ONE launch; z selects weight -------
// wt arena slots are contiguous (2MB each, 256-aligned) -> Wt + z*1048576.
__global__ __launch_bounds__(256) void k_twT6(const float* __restrict__ W0,
                                              const float* __restrict__ W1,
                                              const float* __restrict__ W2,
                                              const float* __restrict__ W3,
                                              const float* __restrict__ W4,
                                              const float* __restrict__ W5,
                                              unsigned short* __restrict__ Wt) {
  __shared__ float t[32][33];
  int z = blockIdx.z;
  const float* W = (z == 0) ? W0 : (z == 1) ? W1 : (z == 2) ? W2
                   : (z == 3) ? W3 : (z == 4) ? W4 : W5;
  unsigned short* T = Wt + (long)z * 1048576;
  int bx = blockIdx.x, by = blockIdx.y;
  int lx = threadIdx.x & 31, ly = threadIdx.x >> 5;
#pragma unroll
  for (int r = 0; r < 4; ++r)
    t[ly + 8 * r][lx] = W[((long)(by * 32 + ly + 8 * r)) * 1024 + bx * 32 + lx];
  __syncthreads();
#pragma unroll
  for (int r = 0; r < 4; ++r)
    T[((long)(bx * 32 + ly + 8 * r)) * 1024 + by * 32 + lx] = f2bf(t[lx][ly + 8 * r]);
}

// ---- fp32 [16][2000][1024] -> bf16 [16][2048][1024], pads zero ------------
__global__ __launch_bounds__(256) void k_cvt_pad(const float* __restrict__ src,
                                                 unsigned short* __restrict__ dst) {
  long idx = (long)blockIdx.x * 256 + threadIdx.x;  // 8-elem chunks
  int b = (int)(idx >> 18);                         // 262144 chunks / batch
  int rem = (int)(idx & 262143);
  int row = rem >> 7;
  int c8 = rem & 127;
  ushort8_t o;
  if (row < 2000) {
    const float* sp = src + ((long)(b * 2000 + row)) * 1024 + c8 * 8;
    float4 f0 = *(const float4*)sp;
    float4 f1 = *(const float4*)(sp + 4);
    o[0] = f2bf(f0.x); o[1] = f2bf(f0.y); o[2] = f2bf(f0.z); o[3] = f2bf(f0.w);
    o[4] = f2bf(f1.x); o[5] = f2bf(f1.y); o[6] = f2bf(f1.z); o[7] = f2bf(f1.w);
  } else {
#pragma unroll
    for (int z = 0; z < 8; ++z) o[z] = 0;
  }
  *(ushort8_t*)(dst + idx * 8) = o;
}

// ---- fp32 -> bf16 plain (query) -------------------------------------------
__global__ __launch_bounds__(256) void k_cvt(const float* __restrict__ src,
                                             unsigned short* __restrict__ dst) {
  long idx = (long)blockIdx.x * 256 + threadIdx.x;
  const float* sp = src + idx * 8;
  float4 f0 = *(const float4*)sp;
  float4 f1 = *(const float4*)(sp + 4);
  ushort8_t o;
  o[0] = f2bf(f0.x); o[1] = f2bf(f0.y); o[2] = f2bf(f0.z); o[3] = f2bf(f0.w);
  o[4] = f2bf(f1.x); o[5] = f2bf(f1.y); o[6] = f2bf(f1.z); o[7] = f2bf(f1.w);
  *(ushort8_t*)(dst + idx * 8) = o;
}

// ---------------------------------------------------------------------------
extern "C" void kernel_launch(void* const* d_in, const int* in_sizes, int n_in,
                              void* d_out, int out_size, void* d_ws, size_t ws_size,
                              hipStream_t stream) {
  const float* key = (const float*)d_in[0];
  const float* value = (const float*)d_in[1];
  const float* query = (const float*)d_in[2];
  const int* mask = (const int*)d_in[3];
  const float* awp = (const float*)d_in[4];
  const float* Wk_ma = (const float*)d_in[5];
  const float* bk_ma = (const float*)d_in[6];
  const float* Wq_ma = (const float*)d_in[7];
  const float* bq_ma = (const float*)d_in[8];
  const float* rvec = (const float*)d_in[9];
  const float* Wk_ca = (const float*)d_in[10];
  const float* bk_ca = (const float*)d_in[11];
  const float* Wq_ca = (const float*)d_in[12];
  const float* bq_ca = (const float*)d_in[13];
  const float* Wv = (const float*)d_in[14];
  const float* bv = (const float*)d_in[15];
  const float* Wo = (const float*)d_in[16];
  const float* bo = (const float*)d_in[17];
  float* outp = (float*)d_out;
  (void)in_sizes; (void)n_in; (void)out_size;

  // arena, 285 MiB
  char* ws = (char*)d_ws;
  size_t off = 0;
  auto alloc = [&](size_t bytes) {
    void* pp = ws + off;
    off += (bytes + 255) & ~(size_t)255;
    return pp;
  };
  unsigned short* wt[6];
  for (int i = 0; i < 6; ++i) wt[i] = (unsigned short*)alloc(1024L * 1024 * 2);
  unsigned short* xbf = (unsigned short*)alloc(16L * 2048 * 1024 * 2);   // key_bf -> value_bf
  unsigned short* qbf = (unsigned short*)alloc(4096L * 1024 * 2);        // query_bf -> cv
  unsigned short* kproj = (unsigned short*)alloc(16L * 2048 * 1024 * 2); // k_ma -> k_ca -> v
  unsigned short* qproj = (unsigned short*)alloc(4096L * 1024 * 2);      // q_ma -> q_ca
  unsigned short* bufP = (unsigned short*)alloc(64L * 256 * 2048 * 2);   // p -> eca -> beta
  unsigned short* bufA = (unsigned short*)alloc(64L * 256 * 2048 * 2);   // cp -> alpha -> vT
  unsigned int* maskw = (unsigned int*)alloc(4096L * 64 * 4);            // packed mask bits
  if (ws_size < off) return;  // fail via absmax, not a fault
  unsigned short* cv_bf = qbf;

  dim3 blk(256);
  // weights (one batched launch) + input conversion
  k_twT6<<<dim3(32, 32, 6), blk, 0, stream>>>(Wk_ma, Wq_ma, Wk_ca, Wq_ca, Wv, Wo, wt[0]);
  k_maskpack<<<dim3(1024), blk, 0, stream>>>(mask, maskw);
  k_cvt_pad<<<dim3(16384), blk, 0, stream>>>(key, xbf);
  k_cvt<<<dim3(2048), blk, 0, stream>>>(query, qbf);
  // MA path
  k_proj<<<dim3(2048), blk, 0, stream>>>(xbf, wt[0], bk_ma, kproj);
  k_proj_d2<<<dim3(256), blk, 0, stream>>>(qbf, wt[1], bq_ma, qproj);
  k_escore<<<dim3(16, 2, 64), blk, 0, stream>>>(qproj, kproj, maskw, rvec, bufP, 1);
  k_cp<<<dim3(16384), blk, 0, stream>>>(bufP, bufA);
  // CA projections (k_ma/q_ma dead; cp lives in bufA)
  k_proj<<<dim3(2048), blk, 0, stream>>>(xbf, wt[2], bk_ca, kproj);
  k_proj_d2<<<dim3(256), blk, 0, stream>>>(qbf, wt[3], bq_ca, qproj);
  // scan: alpha overwrites cp row-by-row (read-before-write)
  k_scan<<<dim3(64), blk, 0, stream>>>(bufP, bufA, awp, bufA);
  // CA scores (p dead) + beta (in-place over eca)
  k_escore<<<dim3(16, 2, 64), blk, 0, stream>>>(qproj, kproj, maskw, rvec, bufP, 0);
  k_beta<<<dim3(16384), blk, 0, stream>>>(bufP, bufA);
  // value path (key dead -> xbf reused; alpha dead -> bufA becomes vT)
  k_cvt_pad<<<dim3(16384), blk, 0, stream>>>(value, xbf);
  k_proj<<<dim3(2048), blk, 0, stream>>>(xbf, wt[4], bv, kproj);
  k_build_vT<<<dim3(32, 4, 64), blk, 0, stream>>>(kproj, bufA);
  // context + output
  k_cv<<<dim3(2, 2, 64), blk, 0, stream>>>(bufP, bufA, cv_bf);
  k_out<<<dim3(8, 32), blk, 0, stream>>>(cv_bf, wt[5], bo, outp);
}